// Round 1
// baseline (1706.761 us; speedup 1.0000x reference)
//
#include <hip/hip_runtime.h>
#include <math.h>

#define N_NODES 50000
#define N_EDGES 800000
#define N_B     64

__device__ __forceinline__ float lrelu(float x){ return x > 0.f ? x : 0.2f*x; }
__device__ __forceinline__ unsigned enc_f(float f){
  unsigned u = __float_as_uint(f);
  return (u & 0x80000000u) ? ~u : (u | 0x80000000u);
}
__device__ __forceinline__ float dec_f(unsigned k){
  return (k & 0x80000000u) ? __uint_as_float(k & 0x7fffffffu) : __uint_as_float(~k);
}

// ---------------- init: zero crit/cnt/mkey/sB/out ----------------
__global__ void k_init(float* crit, int* cnt, unsigned* mkey, float* sB, float* out){
  int i = blockIdx.x*256 + threadIdx.x;
  if (i < N_NODES){ crit[i] = 0.f; cnt[i] = 0; }
  if (i < N_B){ mkey[i] = 0u; sB[i] = 0.f; }          // enc(-inf) > 0, so 0 == "below all"
  if (i < N_B*128){ out[i] = 0.f; }
}

// ---------------- edge MLP -> crit scatter + degree histogram ----------------
__global__ void k_edge(const float* __restrict__ ea, const float* __restrict__ We1,
                       const float* __restrict__ be1, const float* __restrict__ We2,
                       const float* __restrict__ be2, const int* __restrict__ ei,
                       float* __restrict__ crit, int* __restrict__ cnt){
  __shared__ float w0[16], w1[16], bb[16], w2s[16];
  __shared__ float b2s;
  int tid = threadIdx.x;
  if (tid < 16){
    w0[tid] = We1[tid]; w1[tid] = We1[16+tid]; bb[tid] = be1[tid];
    w2s[tid] = 0.25f*(We2[tid*4]+We2[tid*4+1]+We2[tid*4+2]+We2[tid*4+3]);
  }
  if (tid == 0) b2s = 0.25f*(be2[0]+be2[1]+be2[2]+be2[3]);
  __syncthreads();
  int e = blockIdx.x*256 + tid;
  if (e >= N_EDGES) return;
  float a0 = ea[2*e], a1 = ea[2*e+1];
  float s = b2s;
  #pragma unroll
  for (int j = 0; j < 16; j++){
    float v = fmaf(a0, w0[j], fmaf(a1, w1[j], bb[j]));
    v = v > 0.f ? v : 0.f;
    s = fmaf(v, w2s[j], s);
  }
  int d = ei[N_EDGES + e];
  atomicAdd(&crit[d], s);
  atomicAdd(&cnt[d], 1);
}

// ---------------- exclusive scan (3 kernels) + CSR fill ----------------
__global__ void k_scan1(const int* __restrict__ cnt, int* __restrict__ incl, int* __restrict__ part){
  __shared__ int sh[256];
  int tid = threadIdx.x, i = blockIdx.x*256 + tid;
  int v = (i < N_NODES) ? cnt[i] : 0;
  sh[tid] = v; __syncthreads();
  for (int off = 1; off < 256; off <<= 1){
    int t = (tid >= off) ? sh[tid-off] : 0;
    __syncthreads();
    sh[tid] += t; __syncthreads();
  }
  if (i < N_NODES) incl[i] = sh[tid];
  if (tid == 255) part[blockIdx.x] = sh[255];
}
__global__ void k_scan2(const int* __restrict__ part, int* __restrict__ pexcl, int nblocks){
  __shared__ int sh[256];
  int tid = threadIdx.x;
  int v = (tid < nblocks) ? part[tid] : 0;
  sh[tid] = v; __syncthreads();
  for (int off = 1; off < 256; off <<= 1){
    int t = (tid >= off) ? sh[tid-off] : 0;
    __syncthreads();
    sh[tid] += t; __syncthreads();
  }
  if (tid < nblocks) pexcl[tid] = sh[tid] - v;
}
__global__ void k_scan3(const int* __restrict__ cnt, const int* __restrict__ incl,
                        const int* __restrict__ pexcl, int* __restrict__ off, int* __restrict__ cur){
  int i = blockIdx.x*256 + threadIdx.x;
  if (i >= N_NODES) return;
  int e = incl[i] - cnt[i] + pexcl[i >> 8];
  off[i] = e; cur[i] = e;
  if (i == N_NODES-1) off[N_NODES] = e + cnt[i];
}
__global__ void k_fill(const int* __restrict__ ei, int* __restrict__ cur, int* __restrict__ csr){
  int e = blockIdx.x*256 + threadIdx.x;
  if (e >= N_EDGES) return;
  int d = ei[N_EDGES + e];
  int p = atomicAdd(&cur[d], 1);
  csr[p] = ei[e];        // store src
}

// ---------------- node GEMM: out = in[N,128] @ W[128,NC] (+bias) (+attn coeffs) ----------------
template<int NC, bool ATTN, bool BIAS>
__global__ __launch_bounds__(256) void k_gemm(
    const float* __restrict__ in, const float* __restrict__ W,
    const float* __restrict__ bias, const float* __restrict__ a_s,
    const float* __restrict__ a_d, float* __restrict__ out,
    float* __restrict__ asn, float* __restrict__ adn)
{
  constexpr int COLL = NC/4;      // 32 or 16 column-lanes
  constexpr int RG   = 64/COLL;   // 2 or 4 row groups
  constexpr int RPW  = 2*RG;      // rows per wave (2 accumulators)
  constexpr int RPB  = 4*RPW;     // rows per block
  __shared__ float hs[RPB][128];
  int tid = threadIdx.x;
  int wave = tid >> 6, lane = tid & 63;
  int cl = lane % COLL, rg = lane / COLL;
  int c4 = cl*4;
  for (int rbase = blockIdx.x*RPB; rbase < N_NODES; rbase += gridDim.x*RPB){
    __syncthreads();
    for (int i = tid; i < RPB*32; i += 256){
      int r = i >> 5, cc = (i & 31)*4;
      int gr = rbase + r;
      float4 v = make_float4(0.f,0.f,0.f,0.f);
      if (gr < N_NODES) v = *(const float4*)(in + gr*128 + cc);
      *(float4*)(&hs[r][cc]) = v;
    }
    __syncthreads();
    int r0 = wave*RPW + rg, r1 = r0 + RG;
    float ax=0,ay=0,az=0,aw=0, bx=0,by=0,bz=0,bw=0;
    #pragma unroll 4
    for (int k = 0; k < 128; k++){
      float4 w = *(const float4*)(W + k*NC + c4);   // L1/L2-cached, half-wave broadcast
      float h0 = hs[r0][k], h1 = hs[r1][k];
      ax = fmaf(h0,w.x,ax); ay = fmaf(h0,w.y,ay); az = fmaf(h0,w.z,az); aw = fmaf(h0,w.w,aw);
      bx = fmaf(h1,w.x,bx); by = fmaf(h1,w.y,by); bz = fmaf(h1,w.z,bz); bw = fmaf(h1,w.w,bw);
    }
    int gr0 = rbase + r0, gr1 = rbase + r1;
    if (BIAS){
      float4 bv = *(const float4*)(bias + c4);
      ax += bv.x; ay += bv.y; az += bv.z; aw += bv.w;
      bx += bv.x; by += bv.y; bz += bv.z; bw += bv.w;
    }
    if (ATTN){
      // head = c4>>5; a_s index == channel == c4 (contiguous 4)
      int hh = c4 >> 5;
      float4 sa = *(const float4*)(a_s + c4);
      float4 da = *(const float4*)(a_d + c4);
      float pas0 = ax*sa.x + ay*sa.y + az*sa.z + aw*sa.w;
      float pad0 = ax*da.x + ay*da.y + az*da.z + aw*da.w;
      float pas1 = bx*sa.x + by*sa.y + bz*sa.z + bw*sa.w;
      float pad1 = bx*da.x + by*da.y + bz*da.z + bw*da.w;
      #pragma unroll
      for (int m = 1; m < 8; m <<= 1){          // reduce over 8 lanes of same (row, head)
        pas0 += __shfl_xor(pas0, m); pad0 += __shfl_xor(pad0, m);
        pas1 += __shfl_xor(pas1, m); pad1 += __shfl_xor(pad1, m);
      }
      if ((lane & 7) == 0){
        if (gr0 < N_NODES){ asn[gr0*4+hh] = pas0; adn[gr0*4+hh] = pad0; }
        if (gr1 < N_NODES){ asn[gr1*4+hh] = pas1; adn[gr1*4+hh] = pad1; }
      }
    }
    if (gr0 < N_NODES) *(float4*)(&out[gr0*NC + c4]) = make_float4(ax,ay,az,aw);
    if (gr1 < N_NODES) *(float4*)(&out[gr1*NC + c4]) = make_float4(bx,by,bz,bw);
  }
}

// ---------------- per-node GAT softmax + aggregate + bias + LN + crit + residual ----------------
__global__ __launch_bounds__(256) void k_aggr(
    const float* __restrict__ xp, const float* __restrict__ asn,
    const float* __restrict__ adn, const int* __restrict__ off,
    const int* __restrict__ csr, const float* __restrict__ bl,
    const float* __restrict__ lng, const float* __restrict__ lnb,
    const float* __restrict__ crit, float* __restrict__ h)
{
  int wave = threadIdx.x >> 6, lane = threadIdx.x & 63;
  int n = blockIdx.x*4 + wave;
  if (n >= N_NODES) return;
  int base = off[n], deg = off[n+1] - base;
  float4 ad4 = *(const float4*)(adn + n*4);
  float4 asf = *(const float4*)(asn + n*4);
  float ex = lrelu(asf.x+ad4.x), ey = lrelu(asf.y+ad4.y);
  float ez = lrelu(asf.z+ad4.z), ew = lrelu(asf.w+ad4.w);
  float mx = ex, my = ey, mz = ez, mw = ew;
  // pass 1: lane-parallel max over incoming edges
  for (int j = lane; j < deg; j += 64){
    int s = csr[base + j];
    float4 a = *(const float4*)(asn + s*4);
    mx = fmaxf(mx, lrelu(a.x+ad4.x)); my = fmaxf(my, lrelu(a.y+ad4.y));
    mz = fmaxf(mz, lrelu(a.z+ad4.z)); mw = fmaxf(mw, lrelu(a.w+ad4.w));
  }
  #pragma unroll
  for (int m = 1; m < 64; m <<= 1){
    mx = fmaxf(mx, __shfl_xor(mx, m)); my = fmaxf(my, __shfl_xor(my, m));
    mz = fmaxf(mz, __shfl_xor(mz, m)); mw = fmaxf(mw, __shfl_xor(mw, m));
  }
  // self-loop term
  float psx = __expf(ex-mx), psy = __expf(ey-my), psz = __expf(ez-mz), psw = __expf(ew-mw);
  float sx = psx, sy = psy, sz = psz, sw = psw;
  int c0 = lane, c1 = lane + 64;
  bool hi = (lane & 32) != 0;
  float p0 = hi ? psy : psx;       // head of c0 (0 or 1)
  float p1 = hi ? psw : psz;       // head of c1 (2 or 3)
  float acc0 = p0 * xp[n*128 + c0];
  float acc1 = p1 * xp[n*128 + c1];
  // pass 2: wave-sequential edges, all lanes cover 128 channels
  for (int j = 0; j < deg; j++){
    int s = csr[base + j];                      // wave-uniform -> scalar load
    float4 a = *(const float4*)(asn + s*4);     // wave-uniform -> scalar load
    float qx = __expf(lrelu(a.x+ad4.x)-mx);
    float qy = __expf(lrelu(a.y+ad4.y)-my);
    float qz = __expf(lrelu(a.z+ad4.z)-mz);
    float qw = __expf(lrelu(a.w+ad4.w)-mw);
    sx += qx; sy += qy; sz += qz; sw += qw;
    float q0 = hi ? qy : qx, q1 = hi ? qw : qz;
    acc0 = fmaf(q0, xp[s*128 + c0], acc0);      // coalesced 256B
    acc1 = fmaf(q1, xp[s*128 + c1], acc1);
  }
  float den0 = (hi ? sy : sx) + 1e-16f;
  float den1 = (hi ? sw : sz) + 1e-16f;
  float o0 = acc0/den0 + bl[c0];
  float o1 = acc1/den1 + bl[c1];
  // LayerNorm over 128 channels
  float su = o0 + o1, sq = o0*o0 + o1*o1;
  #pragma unroll
  for (int m = 1; m < 64; m <<= 1){ su += __shfl_xor(su, m); sq += __shfl_xor(sq, m); }
  float mu  = su * (1.f/128.f);
  float var = sq * (1.f/128.f) - mu*mu; var = var > 0.f ? var : 0.f;
  float inv = rsqrtf(var + 1e-5f);
  float cr = crit[n];
  float r0 = h[n*128 + c0], r1 = h[n*128 + c1];
  o0 = (o0-mu)*inv*lng[c0] + lnb[c0] + cr + r0;
  o1 = (o1-mu)*inv*lng[c1] + lnb[c1] + cr + r1;
  h[n*128 + c0] = o0; h[n*128 + c1] = o1;
}

// ---------------- pooling ----------------
__global__ void k_gatefin(const float* __restrict__ gpre, const float* __restrict__ Wg2,
                          const float* __restrict__ bg2, const int* __restrict__ batch,
                          float* __restrict__ gate, unsigned* __restrict__ mkey){
  int wave = threadIdx.x >> 6, lane = threadIdx.x & 63;
  int n = blockIdx.x*4 + wave;
  if (n >= N_NODES) return;
  float t = tanhf(gpre[n*64 + lane]);
  float v = t * Wg2[lane];
  #pragma unroll
  for (int m = 1; m < 64; m <<= 1) v += __shfl_xor(v, m);
  if (lane == 0){
    float g = v + bg2[0];
    gate[n] = g;
    atomicMax(&mkey[batch[n]], enc_f(g));
  }
}
__global__ void k_psum(const int* __restrict__ batch, const unsigned* __restrict__ mkey,
                       float* __restrict__ gate, float* __restrict__ sB){
  int i = blockIdx.x*256 + threadIdx.x;
  if (i >= N_NODES) return;
  int b = batch[i];
  float p = __expf(gate[i] - dec_f(mkey[b]));
  gate[i] = p;
  atomicAdd(&sB[b], p);
}
__global__ void k_outacc(const float* __restrict__ h, const float* __restrict__ gate,
                         const float* __restrict__ sB, const int* __restrict__ batch,
                         float* __restrict__ out){
  int wave = threadIdx.x >> 6, lane = threadIdx.x & 63;
  int n = blockIdx.x*4 + wave;
  if (n >= N_NODES) return;
  int b = batch[n];
  float coef = gate[n] / (sB[b] + 1e-16f);
  atomicAdd(&out[b*128 + lane],      coef * h[n*128 + lane]);
  atomicAdd(&out[b*128 + 64 + lane], coef * h[n*128 + 64 + lane]);
}

extern "C" void kernel_launch(void* const* d_in, const int* in_sizes, int n_in,
                              void* d_out, int out_size, void* d_ws, size_t ws_size,
                              hipStream_t stream){
  (void)in_sizes; (void)n_in; (void)out_size; (void)ws_size;
  const float* x    = (const float*)d_in[0];
  const float* ea   = (const float*)d_in[1];
  const float* Win  = (const float*)d_in[2];
  const float* b_in = (const float*)d_in[3];
  const float* We1  = (const float*)d_in[4];
  const float* be1  = (const float*)d_in[5];
  const float* We2  = (const float*)d_in[6];
  const float* be2  = (const float*)d_in[7];
  const float* Wl   = (const float*)d_in[8];
  const float* a_src= (const float*)d_in[9];
  const float* a_dst= (const float*)d_in[10];
  const float* bl   = (const float*)d_in[11];
  const float* lng  = (const float*)d_in[12];
  const float* lnb  = (const float*)d_in[13];
  const float* Wg1  = (const float*)d_in[14];
  const float* bg1  = (const float*)d_in[15];
  const float* Wg2  = (const float*)d_in[16];
  const float* bg2  = (const float*)d_in[17];
  const int*   ei   = (const int*)d_in[18];
  const int*   batch= (const int*)d_in[19];
  float* out = (float*)d_out;

  char* w = (char*)d_ws;
  auto alloc = [&](size_t bytes){ char* p = w; w += (bytes + 255) & ~(size_t)255; return p; };
  float* h    = (float*)alloc((size_t)N_NODES*128*4);
  float* xp   = (float*)alloc((size_t)N_NODES*128*4);
  float* asn  = (float*)alloc((size_t)N_NODES*4*4);
  float* adn  = (float*)alloc((size_t)N_NODES*4*4);
  float* crit = (float*)alloc((size_t)N_NODES*4);
  int*   cnt  = (int*)alloc((size_t)N_NODES*4);
  int*   incl = (int*)alloc((size_t)N_NODES*4);
  int*   part = (int*)alloc(256*4);
  int*   pexc = (int*)alloc(256*4);
  int*   off  = (int*)alloc((size_t)(N_NODES+1)*4);
  int*   cur  = (int*)alloc((size_t)N_NODES*4);
  int*   csr  = (int*)alloc((size_t)N_EDGES*4);
  float* gate = (float*)alloc((size_t)N_NODES*4);
  unsigned* mkey = (unsigned*)alloc(N_B*4);
  float* sB   = (float*)alloc(N_B*4);
  float* gpre = xp;   // alias: xp dead after layers

  int nb_n = (N_NODES + 255)/256;   // 196
  int nb_e = (N_EDGES + 255)/256;   // 3125
  int nb_w = (N_NODES + 3)/4;       // 12500 (one wave per node)

  k_init<<<nb_n,256,0,stream>>>(crit, cnt, mkey, sB, out);
  k_gemm<128,false,true><<<3125,256,0,stream>>>(x, Win, b_in, nullptr, nullptr, h, nullptr, nullptr);
  k_edge<<<nb_e,256,0,stream>>>(ea, We1, be1, We2, be2, ei, crit, cnt);
  k_scan1<<<nb_n,256,0,stream>>>(cnt, incl, part);
  k_scan2<<<1,256,0,stream>>>(part, pexc, nb_n);
  k_scan3<<<nb_n,256,0,stream>>>(cnt, incl, pexc, off, cur);
  k_fill<<<nb_e,256,0,stream>>>(ei, cur, csr);
  for (int l = 0; l < 4; l++){
    k_gemm<128,true,false><<<3125,256,0,stream>>>(h, Wl + (size_t)l*128*128, nullptr,
                                                  a_src + l*128, a_dst + l*128, xp, asn, adn);
    k_aggr<<<nb_w,256,0,stream>>>(xp, asn, adn, off, csr,
                                  bl + l*128, lng + l*128, lnb + l*128, crit, h);
  }
  k_gemm<64,false,true><<<1563,256,0,stream>>>(h, Wg1, bg1, nullptr, nullptr, gpre, nullptr, nullptr);
  k_gatefin<<<nb_w,256,0,stream>>>(gpre, Wg2, bg2, batch, gate, mkey);
  k_psum<<<nb_n,256,0,stream>>>(batch, mkey, gate, sB);
  k_outacc<<<nb_w,256,0,stream>>>(h, gate, sB, batch, out);
}

// Round 2
// 1019.798 us; speedup vs baseline: 1.6736x; 1.6736x over previous
//
#include <hip/hip_runtime.h>
#include <math.h>

#define N_NODES 50000
#define N_EDGES 800000
#define N_B     64

__device__ __forceinline__ float lrelu(float x){ return x > 0.f ? x : 0.2f*x; }

// ---------------- init: zero crit/cnt ----------------
__global__ void k_init(float* crit, int* cnt){
  int i = blockIdx.x*256 + threadIdx.x;
  if (i < N_NODES){ crit[i] = 0.f; cnt[i] = 0; }
}

// ---------------- edge MLP -> crit scatter + degree histogram ----------------
__global__ void k_edge(const float* __restrict__ ea, const float* __restrict__ We1,
                       const float* __restrict__ be1, const float* __restrict__ We2,
                       const float* __restrict__ be2, const int* __restrict__ ei,
                       float* __restrict__ crit, int* __restrict__ cnt){
  __shared__ float w0[16], w1[16], bb[16], w2s[16];
  __shared__ float b2s;
  int tid = threadIdx.x;
  if (tid < 16){
    w0[tid] = We1[tid]; w1[tid] = We1[16+tid]; bb[tid] = be1[tid];
    w2s[tid] = 0.25f*(We2[tid*4]+We2[tid*4+1]+We2[tid*4+2]+We2[tid*4+3]);
  }
  if (tid == 0) b2s = 0.25f*(be2[0]+be2[1]+be2[2]+be2[3]);
  __syncthreads();
  int e = blockIdx.x*256 + tid;
  if (e >= N_EDGES) return;
  float a0 = ea[2*e], a1 = ea[2*e+1];
  float s = b2s;
  #pragma unroll
  for (int j = 0; j < 16; j++){
    float v = fmaf(a0, w0[j], fmaf(a1, w1[j], bb[j]));
    v = v > 0.f ? v : 0.f;
    s = fmaf(v, w2s[j], s);
  }
  int d = ei[N_EDGES + e];
  atomicAdd(&crit[d], s);
  atomicAdd(&cnt[d], 1);
}

// ---------------- exclusive scan (3 kernels) + CSR fill ----------------
__global__ void k_scan1(const int* __restrict__ cnt, int* __restrict__ incl, int* __restrict__ part){
  __shared__ int sh[256];
  int tid = threadIdx.x, i = blockIdx.x*256 + tid;
  int v = (i < N_NODES) ? cnt[i] : 0;
  sh[tid] = v; __syncthreads();
  for (int off = 1; off < 256; off <<= 1){
    int t = (tid >= off) ? sh[tid-off] : 0;
    __syncthreads();
    sh[tid] += t; __syncthreads();
  }
  if (i < N_NODES) incl[i] = sh[tid];
  if (tid == 255) part[blockIdx.x] = sh[255];
}
__global__ void k_scan2(const int* __restrict__ part, int* __restrict__ pexcl, int nblocks){
  __shared__ int sh[256];
  int tid = threadIdx.x;
  int v = (tid < nblocks) ? part[tid] : 0;
  sh[tid] = v; __syncthreads();
  for (int off = 1; off < 256; off <<= 1){
    int t = (tid >= off) ? sh[tid-off] : 0;
    __syncthreads();
    sh[tid] += t; __syncthreads();
  }
  if (tid < nblocks) pexcl[tid] = sh[tid] - v;
}
__global__ void k_scan3(const int* __restrict__ cnt, const int* __restrict__ incl,
                        const int* __restrict__ pexcl, int* __restrict__ off, int* __restrict__ cur){
  int i = blockIdx.x*256 + threadIdx.x;
  if (i >= N_NODES) return;
  int e = incl[i] - cnt[i] + pexcl[i >> 8];
  off[i] = e; cur[i] = e;
  if (i == N_NODES-1) off[N_NODES] = e + cnt[i];
}
__global__ void k_fill(const int* __restrict__ ei, int* __restrict__ cur, int* __restrict__ csr){
  int e = blockIdx.x*256 + threadIdx.x;
  if (e >= N_EDGES) return;
  int d = ei[N_EDGES + e];
  int p = atomicAdd(&cur[d], 1);
  csr[p] = ei[e];        // store src
}

// ---------------- graph boundaries (batch is sorted) ----------------
__global__ void k_bounds(const int* __restrict__ batch, int* __restrict__ start){
  int i = blockIdx.x*256 + threadIdx.x;
  if (i >= N_NODES) return;
  int b = batch[i];
  int bp = (i == 0) ? -1 : batch[i-1];
  for (int j = bp+1; j <= b; j++) start[j] = i;
  if (i == N_NODES-1){
    for (int j = b+1; j <= N_B; j++) start[j] = N_NODES;
  }
}

// ---------------- node GEMM: out = in[N,128] @ W[128,NC] (+bias) (+attn coeffs) ----------------
template<int NC, bool ATTN, bool BIAS>
__global__ __launch_bounds__(256) void k_gemm(
    const float* __restrict__ in, const float* __restrict__ W,
    const float* __restrict__ bias, const float* __restrict__ a_s,
    const float* __restrict__ a_d, float* __restrict__ out,
    float* __restrict__ asn, float* __restrict__ adn)
{
  constexpr int COLL = NC/4;      // 32 or 16 column-lanes
  constexpr int RG   = 64/COLL;   // 2 or 4 row groups
  constexpr int RPW  = 2*RG;      // rows per wave (2 accumulators)
  constexpr int RPB  = 4*RPW;     // rows per block
  __shared__ float hs[RPB][128];
  int tid = threadIdx.x;
  int wave = tid >> 6, lane = tid & 63;
  int cl = lane % COLL, rg = lane / COLL;
  int c4 = cl*4;
  for (int rbase = blockIdx.x*RPB; rbase < N_NODES; rbase += gridDim.x*RPB){
    __syncthreads();
    for (int i = tid; i < RPB*32; i += 256){
      int r = i >> 5, cc = (i & 31)*4;
      int gr = rbase + r;
      float4 v = make_float4(0.f,0.f,0.f,0.f);
      if (gr < N_NODES) v = *(const float4*)(in + gr*128 + cc);
      *(float4*)(&hs[r][cc]) = v;
    }
    __syncthreads();
    int r0 = wave*RPW + rg, r1 = r0 + RG;
    float ax=0,ay=0,az=0,aw=0, bx=0,by=0,bz=0,bw=0;
    #pragma unroll 4
    for (int k = 0; k < 128; k++){
      float4 w = *(const float4*)(W + k*NC + c4);   // L1/L2-cached, half-wave broadcast
      float h0 = hs[r0][k], h1 = hs[r1][k];
      ax = fmaf(h0,w.x,ax); ay = fmaf(h0,w.y,ay); az = fmaf(h0,w.z,az); aw = fmaf(h0,w.w,aw);
      bx = fmaf(h1,w.x,bx); by = fmaf(h1,w.y,by); bz = fmaf(h1,w.z,bz); bw = fmaf(h1,w.w,bw);
    }
    int gr0 = rbase + r0, gr1 = rbase + r1;
    if (BIAS){
      float4 bv = *(const float4*)(bias + c4);
      ax += bv.x; ay += bv.y; az += bv.z; aw += bv.w;
      bx += bv.x; by += bv.y; bz += bv.z; bw += bv.w;
    }
    if (ATTN){
      int hh = c4 >> 5;
      float4 sa = *(const float4*)(a_s + c4);
      float4 da = *(const float4*)(a_d + c4);
      float pas0 = ax*sa.x + ay*sa.y + az*sa.z + aw*sa.w;
      float pad0 = ax*da.x + ay*da.y + az*da.z + aw*da.w;
      float pas1 = bx*sa.x + by*sa.y + bz*sa.z + bw*sa.w;
      float pad1 = bx*da.x + by*da.y + bz*da.z + bw*da.w;
      #pragma unroll
      for (int m = 1; m < 8; m <<= 1){
        pas0 += __shfl_xor(pas0, m); pad0 += __shfl_xor(pad0, m);
        pas1 += __shfl_xor(pas1, m); pad1 += __shfl_xor(pad1, m);
      }
      if ((lane & 7) == 0){
        if (gr0 < N_NODES){ asn[gr0*4+hh] = pas0; adn[gr0*4+hh] = pad0; }
        if (gr1 < N_NODES){ asn[gr1*4+hh] = pas1; adn[gr1*4+hh] = pad1; }
      }
    }
    if (gr0 < N_NODES) *(float4*)(&out[gr0*NC + c4]) = make_float4(ax,ay,az,aw);
    if (gr1 < N_NODES) *(float4*)(&out[gr1*NC + c4]) = make_float4(bx,by,bz,bw);
  }
}

// ---------------- per-node GAT softmax + aggregate + bias + LN + crit + residual ----------------
__global__ __launch_bounds__(256) void k_aggr(
    const float* __restrict__ xp, const float* __restrict__ asn,
    const float* __restrict__ adn, const int* __restrict__ off,
    const int* __restrict__ csr, const float* __restrict__ bl,
    const float* __restrict__ lng, const float* __restrict__ lnb,
    const float* __restrict__ crit, float* __restrict__ h)
{
  int wave = threadIdx.x >> 6, lane = threadIdx.x & 63;
  int n = blockIdx.x*4 + wave;
  if (n >= N_NODES) return;
  int base = off[n], deg = off[n+1] - base;
  float4 ad4 = *(const float4*)(adn + n*4);
  float4 asf = *(const float4*)(asn + n*4);
  float ex = lrelu(asf.x+ad4.x), ey = lrelu(asf.y+ad4.y);
  float ez = lrelu(asf.z+ad4.z), ew = lrelu(asf.w+ad4.w);
  float mx = ex, my = ey, mz = ez, mw = ew;
  for (int j = lane; j < deg; j += 64){
    int s = csr[base + j];
    float4 a = *(const float4*)(asn + s*4);
    mx = fmaxf(mx, lrelu(a.x+ad4.x)); my = fmaxf(my, lrelu(a.y+ad4.y));
    mz = fmaxf(mz, lrelu(a.z+ad4.z)); mw = fmaxf(mw, lrelu(a.w+ad4.w));
  }
  #pragma unroll
  for (int m = 1; m < 64; m <<= 1){
    mx = fmaxf(mx, __shfl_xor(mx, m)); my = fmaxf(my, __shfl_xor(my, m));
    mz = fmaxf(mz, __shfl_xor(mz, m)); mw = fmaxf(mw, __shfl_xor(mw, m));
  }
  float psx = __expf(ex-mx), psy = __expf(ey-my), psz = __expf(ez-mz), psw = __expf(ew-mw);
  float sx = psx, sy = psy, sz = psz, sw = psw;
  int c0 = lane, c1 = lane + 64;
  bool hi = (lane & 32) != 0;
  float p0 = hi ? psy : psx;
  float p1 = hi ? psw : psz;
  float acc0 = p0 * xp[n*128 + c0];
  float acc1 = p1 * xp[n*128 + c1];
  for (int j = 0; j < deg; j++){
    int s = csr[base + j];
    float4 a = *(const float4*)(asn + s*4);
    float qx = __expf(lrelu(a.x+ad4.x)-mx);
    float qy = __expf(lrelu(a.y+ad4.y)-my);
    float qz = __expf(lrelu(a.z+ad4.z)-mz);
    float qw = __expf(lrelu(a.w+ad4.w)-mw);
    sx += qx; sy += qy; sz += qz; sw += qw;
    float q0 = hi ? qy : qx, q1 = hi ? qw : qz;
    acc0 = fmaf(q0, xp[s*128 + c0], acc0);
    acc1 = fmaf(q1, xp[s*128 + c1], acc1);
  }
  float den0 = (hi ? sy : sx) + 1e-16f;
  float den1 = (hi ? sw : sz) + 1e-16f;
  float o0 = acc0/den0 + bl[c0];
  float o1 = acc1/den1 + bl[c1];
  float su = o0 + o1, sq = o0*o0 + o1*o1;
  #pragma unroll
  for (int m = 1; m < 64; m <<= 1){ su += __shfl_xor(su, m); sq += __shfl_xor(sq, m); }
  float mu  = su * (1.f/128.f);
  float var = sq * (1.f/128.f) - mu*mu; var = var > 0.f ? var : 0.f;
  float inv = rsqrtf(var + 1e-5f);
  float cr = crit[n];
  float r0 = h[n*128 + c0], r1 = h[n*128 + c1];
  o0 = (o0-mu)*inv*lng[c0] + lnb[c0] + cr + r0;
  o1 = (o1-mu)*inv*lng[c1] + lnb[c1] + cr + r1;
  h[n*128 + c0] = o0; h[n*128 + c1] = o1;
}

// ---------------- pooling: gate scalar (no atomics) ----------------
__global__ void k_gatefin(const float* __restrict__ gpre, const float* __restrict__ Wg2,
                          const float* __restrict__ bg2,
                          float* __restrict__ gate){
  int wave = threadIdx.x >> 6, lane = threadIdx.x & 63;
  int n = blockIdx.x*4 + wave;
  if (n >= N_NODES) return;
  float t = tanhf(gpre[n*64 + lane]);
  float v = t * Wg2[lane];
  #pragma unroll
  for (int m = 1; m < 64; m <<= 1) v += __shfl_xor(v, m);
  if (lane == 0) gate[n] = v + bg2[0];
}

// ---------------- pooling: one block per graph, atomic-free ----------------
__global__ __launch_bounds__(256) void k_pool(
    const float* __restrict__ h, float* __restrict__ gate,
    const int* __restrict__ start, float* __restrict__ out)
{
  __shared__ float red[4];
  __shared__ float sbc;
  __shared__ float4 accs[8][32];
  int b = blockIdx.x;
  int s0 = start[b], s1 = start[b+1];
  int tid = threadIdx.x, lane = tid & 63, wave = tid >> 6;
  // phase A: segment max
  float m = -3.0e38f;
  for (int i = s0 + tid; i < s1; i += 256) m = fmaxf(m, gate[i]);
  #pragma unroll
  for (int k = 1; k < 64; k <<= 1) m = fmaxf(m, __shfl_xor(m, k));
  if (lane == 0) red[wave] = m;
  __syncthreads();
  if (tid == 0) sbc = fmaxf(fmaxf(red[0],red[1]), fmaxf(red[2],red[3]));
  __syncthreads();
  float gm = sbc;
  __syncthreads();
  // phase B: exp + segment sum (overwrite gate with p; nodes owned exclusively by this block)
  float s = 0.f;
  for (int i = s0 + tid; i < s1; i += 256){
    float p = __expf(gate[i] - gm);
    gate[i] = p;
    s += p;
  }
  #pragma unroll
  for (int k = 1; k < 64; k <<= 1) s += __shfl_xor(s, k);
  if (lane == 0) red[wave] = s;
  __syncthreads();
  if (tid == 0) sbc = red[0]+red[1]+red[2]+red[3];
  __syncthreads();
  float inv = 1.f / (sbc + 1e-16f);
  // phase C: weighted accumulate, 8 node-groups x 32 channel-quads
  int c4 = (tid & 31) * 4;
  int g  = tid >> 5;
  float4 acc = make_float4(0.f,0.f,0.f,0.f);
  for (int i = s0 + g; i < s1; i += 8){
    float p = gate[i];
    float4 hv = *(const float4*)(h + i*128 + c4);
    acc.x = fmaf(p,hv.x,acc.x); acc.y = fmaf(p,hv.y,acc.y);
    acc.z = fmaf(p,hv.z,acc.z); acc.w = fmaf(p,hv.w,acc.w);
  }
  accs[g][tid & 31] = acc;
  __syncthreads();
  if (g == 0){
    float4 t = acc;
    #pragma unroll
    for (int k = 1; k < 8; k++){
      float4 o = accs[k][tid & 31];
      t.x += o.x; t.y += o.y; t.z += o.z; t.w += o.w;
    }
    t.x *= inv; t.y *= inv; t.z *= inv; t.w *= inv;
    *(float4*)(out + b*128 + c4) = t;
  }
}

extern "C" void kernel_launch(void* const* d_in, const int* in_sizes, int n_in,
                              void* d_out, int out_size, void* d_ws, size_t ws_size,
                              hipStream_t stream){
  (void)in_sizes; (void)n_in; (void)out_size; (void)ws_size;
  const float* x    = (const float*)d_in[0];
  const float* ea   = (const float*)d_in[1];
  const float* Win  = (const float*)d_in[2];
  const float* b_in = (const float*)d_in[3];
  const float* We1  = (const float*)d_in[4];
  const float* be1  = (const float*)d_in[5];
  const float* We2  = (const float*)d_in[6];
  const float* be2  = (const float*)d_in[7];
  const float* Wl   = (const float*)d_in[8];
  const float* a_src= (const float*)d_in[9];
  const float* a_dst= (const float*)d_in[10];
  const float* bl   = (const float*)d_in[11];
  const float* lng  = (const float*)d_in[12];
  const float* lnb  = (const float*)d_in[13];
  const float* Wg1  = (const float*)d_in[14];
  const float* bg1  = (const float*)d_in[15];
  const float* Wg2  = (const float*)d_in[16];
  const float* bg2  = (const float*)d_in[17];
  const int*   ei   = (const int*)d_in[18];
  const int*   batch= (const int*)d_in[19];
  float* out = (float*)d_out;

  char* w = (char*)d_ws;
  auto alloc = [&](size_t bytes){ char* p = w; w += (bytes + 255) & ~(size_t)255; return p; };
  float* h    = (float*)alloc((size_t)N_NODES*128*4);
  float* xp   = (float*)alloc((size_t)N_NODES*128*4);
  float* asn  = (float*)alloc((size_t)N_NODES*4*4);
  float* adn  = (float*)alloc((size_t)N_NODES*4*4);
  float* crit = (float*)alloc((size_t)N_NODES*4);
  int*   cnt  = (int*)alloc((size_t)N_NODES*4);
  int*   incl = (int*)alloc((size_t)N_NODES*4);
  int*   part = (int*)alloc(256*4);
  int*   pexc = (int*)alloc(256*4);
  int*   off  = (int*)alloc((size_t)(N_NODES+1)*4);
  int*   cur  = (int*)alloc((size_t)N_NODES*4);
  int*   csr  = (int*)alloc((size_t)N_EDGES*4);
  float* gate = (float*)alloc((size_t)N_NODES*4);
  int*   start= (int*)alloc((size_t)(N_B+1)*4);
  float* gpre = xp;   // alias: xp dead after layers

  int nb_n = (N_NODES + 255)/256;   // 196
  int nb_e = (N_EDGES + 255)/256;   // 3125
  int nb_w = (N_NODES + 3)/4;       // 12500 (one wave per node)

  k_init<<<nb_n,256,0,stream>>>(crit, cnt);
  k_bounds<<<nb_n,256,0,stream>>>(batch, start);
  k_gemm<128,false,true><<<3125,256,0,stream>>>(x, Win, b_in, nullptr, nullptr, h, nullptr, nullptr);
  k_edge<<<nb_e,256,0,stream>>>(ea, We1, be1, We2, be2, ei, crit, cnt);
  k_scan1<<<nb_n,256,0,stream>>>(cnt, incl, part);
  k_scan2<<<1,256,0,stream>>>(part, pexc, nb_n);
  k_scan3<<<nb_n,256,0,stream>>>(cnt, incl, pexc, off, cur);
  k_fill<<<nb_e,256,0,stream>>>(ei, cur, csr);
  for (int l = 0; l < 4; l++){
    k_gemm<128,true,false><<<3125,256,0,stream>>>(h, Wl + (size_t)l*128*128, nullptr,
                                                  a_src + l*128, a_dst + l*128, xp, asn, adn);
    k_aggr<<<nb_w,256,0,stream>>>(xp, asn, adn, off, csr,
                                  bl + l*128, lng + l*128, lnb + l*128, crit, h);
  }
  k_gemm<64,false,true><<<1563,256,0,stream>>>(h, Wg1, bg1, nullptr, nullptr, gpre, nullptr, nullptr);
  k_gatefin<<<nb_w,256,0,stream>>>(gpre, Wg2, bg2, gate);
  k_pool<<<N_B,256,0,stream>>>(h, gate, start, out);
}

// Round 3
// 872.726 us; speedup vs baseline: 1.9557x; 1.1685x over previous
//
#include <hip/hip_runtime.h>
#include <math.h>

#define N_NODES 50000
#define N_EDGES 800000
#define N_B     64

__device__ __forceinline__ float lrelu(float x){ return x > 0.f ? x : 0.2f*x; }

// ---------------- setup: zero crit/cnt + graph boundaries (batch sorted) ----------------
__global__ void k_setup(const int* __restrict__ batch, int* __restrict__ start,
                        float* __restrict__ crit, int* __restrict__ cnt){
  int i = blockIdx.x*256 + threadIdx.x;
  if (i >= N_NODES) return;
  crit[i] = 0.f; cnt[i] = 0;
  int b = batch[i];
  int bp = (i == 0) ? -1 : batch[i-1];
  for (int j = bp+1; j <= b; j++) start[j] = i;
  if (i == N_NODES-1){
    for (int j = b+1; j <= N_B; j++) start[j] = N_NODES;
  }
}

// ---------------- edge MLP -> crit scatter + degree histogram ----------------
__global__ void k_edge(const float* __restrict__ ea, const float* __restrict__ We1,
                       const float* __restrict__ be1, const float* __restrict__ We2,
                       const float* __restrict__ be2, const int* __restrict__ ei,
                       float* __restrict__ crit, int* __restrict__ cnt){
  __shared__ float w0[16], w1[16], bb[16], w2s[16];
  __shared__ float b2s;
  int tid = threadIdx.x;
  if (tid < 16){
    w0[tid] = We1[tid]; w1[tid] = We1[16+tid]; bb[tid] = be1[tid];
    w2s[tid] = 0.25f*(We2[tid*4]+We2[tid*4+1]+We2[tid*4+2]+We2[tid*4+3]);
  }
  if (tid == 0) b2s = 0.25f*(be2[0]+be2[1]+be2[2]+be2[3]);
  __syncthreads();
  int e = blockIdx.x*256 + tid;
  if (e >= N_EDGES) return;
  float a0 = ea[2*e], a1 = ea[2*e+1];
  float s = b2s;
  #pragma unroll
  for (int j = 0; j < 16; j++){
    float v = fmaf(a0, w0[j], fmaf(a1, w1[j], bb[j]));
    v = v > 0.f ? v : 0.f;
    s = fmaf(v, w2s[j], s);
  }
  int d = ei[N_EDGES + e];
  atomicAdd(&crit[d], s);
  atomicAdd(&cnt[d], 1);
}

// ---------------- exclusive scan (3 kernels) + CSR fill ----------------
__global__ void k_scan1(const int* __restrict__ cnt, int* __restrict__ incl, int* __restrict__ part){
  __shared__ int sh[256];
  int tid = threadIdx.x, i = blockIdx.x*256 + tid;
  int v = (i < N_NODES) ? cnt[i] : 0;
  sh[tid] = v; __syncthreads();
  for (int off = 1; off < 256; off <<= 1){
    int t = (tid >= off) ? sh[tid-off] : 0;
    __syncthreads();
    sh[tid] += t; __syncthreads();
  }
  if (i < N_NODES) incl[i] = sh[tid];
  if (tid == 255) part[blockIdx.x] = sh[255];
}
__global__ void k_scan2(const int* __restrict__ part, int* __restrict__ pexcl, int nblocks){
  __shared__ int sh[256];
  int tid = threadIdx.x;
  int v = (tid < nblocks) ? part[tid] : 0;
  sh[tid] = v; __syncthreads();
  for (int off = 1; off < 256; off <<= 1){
    int t = (tid >= off) ? sh[tid-off] : 0;
    __syncthreads();
    sh[tid] += t; __syncthreads();
  }
  if (tid < nblocks) pexcl[tid] = sh[tid] - v;
}
__global__ void k_scan3(const int* __restrict__ cnt, const int* __restrict__ incl,
                        const int* __restrict__ pexcl, int* __restrict__ off, int* __restrict__ cur){
  int i = blockIdx.x*256 + threadIdx.x;
  if (i >= N_NODES) return;
  int e = incl[i] - cnt[i] + pexcl[i >> 8];
  off[i] = e; cur[i] = e;
  if (i == N_NODES-1) off[N_NODES] = e + cnt[i];
}
__global__ void k_fill(const int* __restrict__ ei, int* __restrict__ cur, int* __restrict__ csr){
  int e = blockIdx.x*256 + threadIdx.x;
  if (e >= N_EDGES) return;
  int d = ei[N_EDGES + e];
  int p = atomicAdd(&cur[d], 1);
  csr[p] = ei[e];        // store src
}

// ---------------- node GEMM: out = in[N,128] @ W[128,NC] (+bias)(+attn)(+gate) ----------------
template<int NC, bool ATTN, bool BIAS, bool GATE>
__global__ __launch_bounds__(256) void k_gemm(
    const float* __restrict__ in, const float* __restrict__ W,
    const float* __restrict__ bias, const float* __restrict__ a_s,
    const float* __restrict__ a_d, float* __restrict__ out,
    float* __restrict__ asn, float* __restrict__ adn,
    const float* __restrict__ Wg2, const float* __restrict__ bg2,
    float* __restrict__ gate)
{
  constexpr int COLL = NC/4;      // 32 or 16 column-lanes
  constexpr int RG   = 64/COLL;   // 2 or 4 row groups
  constexpr int RPW  = 2*RG;      // rows per wave (2 accumulators)
  constexpr int RPB  = 4*RPW;     // rows per block
  __shared__ float hs[RPB][128];
  int tid = threadIdx.x;
  int wave = tid >> 6, lane = tid & 63;
  int cl = lane % COLL, rg = lane / COLL;
  int c4 = cl*4;
  for (int rbase = blockIdx.x*RPB; rbase < N_NODES; rbase += gridDim.x*RPB){
    __syncthreads();
    for (int i = tid; i < RPB*32; i += 256){
      int r = i >> 5, cc = (i & 31)*4;
      int gr = rbase + r;
      float4 v = make_float4(0.f,0.f,0.f,0.f);
      if (gr < N_NODES) v = *(const float4*)(in + gr*128 + cc);
      *(float4*)(&hs[r][cc]) = v;
    }
    __syncthreads();
    int r0 = wave*RPW + rg, r1 = r0 + RG;
    float ax=0,ay=0,az=0,aw=0, bx=0,by=0,bz=0,bw=0;
    #pragma unroll 4
    for (int k = 0; k < 128; k++){
      float4 w = *(const float4*)(W + k*NC + c4);   // L1/L2-cached, half-wave broadcast
      float h0 = hs[r0][k], h1 = hs[r1][k];
      ax = fmaf(h0,w.x,ax); ay = fmaf(h0,w.y,ay); az = fmaf(h0,w.z,az); aw = fmaf(h0,w.w,aw);
      bx = fmaf(h1,w.x,bx); by = fmaf(h1,w.y,by); bz = fmaf(h1,w.z,bz); bw = fmaf(h1,w.w,bw);
    }
    int gr0 = rbase + r0, gr1 = rbase + r1;
    if (BIAS){
      float4 bv = *(const float4*)(bias + c4);
      ax += bv.x; ay += bv.y; az += bv.z; aw += bv.w;
      bx += bv.x; by += bv.y; bz += bv.z; bw += bv.w;
    }
    if (ATTN){
      int hh = c4 >> 5;
      float4 sa = *(const float4*)(a_s + c4);
      float4 da = *(const float4*)(a_d + c4);
      float pas0 = ax*sa.x + ay*sa.y + az*sa.z + aw*sa.w;
      float pad0 = ax*da.x + ay*da.y + az*da.z + aw*da.w;
      float pas1 = bx*sa.x + by*sa.y + bz*sa.z + bw*sa.w;
      float pad1 = bx*da.x + by*da.y + bz*da.z + bw*da.w;
      #pragma unroll
      for (int m = 1; m < 8; m <<= 1){
        pas0 += __shfl_xor(pas0, m); pad0 += __shfl_xor(pad0, m);
        pas1 += __shfl_xor(pas1, m); pad1 += __shfl_xor(pad1, m);
      }
      if ((lane & 7) == 0){
        if (gr0 < N_NODES){ asn[gr0*4+hh] = pas0; adn[gr0*4+hh] = pad0; }
        if (gr1 < N_NODES){ asn[gr1*4+hh] = pas1; adn[gr1*4+hh] = pad1; }
      }
    }
    if (GATE){
      // gate[row] = sum_c tanh(o[row,c]) * Wg2[c] + bg2  (row owned by 16 lanes)
      float4 w2 = *(const float4*)(Wg2 + c4);
      float v0 = tanhf(ax)*w2.x + tanhf(ay)*w2.y + tanhf(az)*w2.z + tanhf(aw)*w2.w;
      float v1 = tanhf(bx)*w2.x + tanhf(by)*w2.y + tanhf(bz)*w2.z + tanhf(bw)*w2.w;
      #pragma unroll
      for (int m = 1; m < 16; m <<= 1){ v0 += __shfl_xor(v0, m); v1 += __shfl_xor(v1, m); }
      if (cl == 0){
        float b2 = bg2[0];
        if (gr0 < N_NODES) gate[gr0] = v0 + b2;
        if (gr1 < N_NODES) gate[gr1] = v1 + b2;
      }
    } else {
      if (gr0 < N_NODES) *(float4*)(&out[gr0*NC + c4]) = make_float4(ax,ay,az,aw);
      if (gr1 < N_NODES) *(float4*)(&out[gr1*NC + c4]) = make_float4(bx,by,bz,bw);
    }
  }
}

// ---------------- per-node GAT softmax + aggregate + bias + LN + crit + residual ----------------
// v2: softmax numerators computed lane-parallel once per edge, broadcast via per-wave LDS slice.
__global__ __launch_bounds__(256) void k_aggr(
    const float* __restrict__ xp, const float* __restrict__ asn,
    const float* __restrict__ adn, const int* __restrict__ off,
    const int* __restrict__ csr, const float* __restrict__ bl,
    const float* __restrict__ lng, const float* __restrict__ lnb,
    const float* __restrict__ crit, float* __restrict__ h)
{
  __shared__ float lp[4][4*64];        // per-wave slice: [head*64 + j]
  int wave = threadIdx.x >> 6, lane = threadIdx.x & 63;
  int n = blockIdx.x*4 + wave;
  if (n >= N_NODES) return;            // no __syncthreads below: waves independent
  int base = off[n], deg = off[n+1] - base;
  float4 ad4 = *(const float4*)(adn + n*4);
  float4 asf = *(const float4*)(asn + n*4);
  float ex = lrelu(asf.x+ad4.x), ey = lrelu(asf.y+ad4.y);
  float ez = lrelu(asf.z+ad4.z), ew = lrelu(asf.w+ad4.w);
  float mx = ex, my = ey, mz = ez, mw = ew;
  // pass 1: lane-parallel max over incoming edges
  for (int j = lane; j < deg; j += 64){
    int s = csr[base + j];
    float4 a = *(const float4*)(asn + s*4);
    mx = fmaxf(mx, lrelu(a.x+ad4.x)); my = fmaxf(my, lrelu(a.y+ad4.y));
    mz = fmaxf(mz, lrelu(a.z+ad4.z)); mw = fmaxf(mw, lrelu(a.w+ad4.w));
  }
  #pragma unroll
  for (int m = 1; m < 64; m <<= 1){
    mx = fmaxf(mx, __shfl_xor(mx, m)); my = fmaxf(my, __shfl_xor(my, m));
    mz = fmaxf(mz, __shfl_xor(mz, m)); mw = fmaxf(mw, __shfl_xor(mw, m));
  }
  // self-loop numerators (wave-uniform)
  float psx = __expf(ex-mx), psy = __expf(ey-my), psz = __expf(ez-mz), psw = __expf(ew-mw);
  int c0 = lane, c1 = lane + 64;
  bool hi = (lane & 32) != 0;
  float acc0 = (hi ? psy : psx) * xp[n*128 + c0];
  float acc1 = (hi ? psw : psz) * xp[n*128 + c1];
  float sx = 0.f, sy = 0.f, sz = 0.f, sw = 0.f;   // lane-partial denominators
  float* myp = &lp[wave][0];
  int h0off = hi ? 64 : 0, h1off = hi ? 192 : 128;
  // pass 2: 64-edge tiles — compute numerators lane-parallel, accumulate wave-sequential
  for (int j0 = 0; j0 < deg; j0 += 64){
    int clen = deg - j0; if (clen > 64) clen = 64;
    float p0 = 0.f, p1 = 0.f, p2 = 0.f, p3 = 0.f;
    if (lane < clen){
      int s = csr[base + j0 + lane];
      float4 a = *(const float4*)(asn + s*4);
      p0 = __expf(lrelu(a.x+ad4.x)-mx);
      p1 = __expf(lrelu(a.y+ad4.y)-my);
      p2 = __expf(lrelu(a.z+ad4.z)-mz);
      p3 = __expf(lrelu(a.w+ad4.w)-mw);
      sx += p0; sy += p1; sz += p2; sw += p3;
    }
    myp[lane] = p0; myp[64+lane] = p1; myp[128+lane] = p2; myp[192+lane] = p3;
    __threadfence_block();   // order ds_write -> ds_read within the wave
    for (int c = 0; c < clen; c++){
      int s = csr[base + j0 + c];
      float q0 = myp[h0off + c], q1 = myp[h1off + c];
      acc0 = fmaf(q0, xp[s*128 + c0], acc0);
      acc1 = fmaf(q1, xp[s*128 + c1], acc1);
    }
    __threadfence_block();   // reads drained before next tile's writes
  }
  // reduce denominators across lanes, then add (wave-uniform) self terms
  #pragma unroll
  for (int m = 1; m < 64; m <<= 1){
    sx += __shfl_xor(sx, m); sy += __shfl_xor(sy, m);
    sz += __shfl_xor(sz, m); sw += __shfl_xor(sw, m);
  }
  sx += psx; sy += psy; sz += psz; sw += psw;
  float den0 = (hi ? sy : sx) + 1e-16f;
  float den1 = (hi ? sw : sz) + 1e-16f;
  float o0 = acc0/den0 + bl[c0];
  float o1 = acc1/den1 + bl[c1];
  // LayerNorm over 128 channels
  float su = o0 + o1, sq = o0*o0 + o1*o1;
  #pragma unroll
  for (int m = 1; m < 64; m <<= 1){ su += __shfl_xor(su, m); sq += __shfl_xor(sq, m); }
  float mu  = su * (1.f/128.f);
  float var = sq * (1.f/128.f) - mu*mu; var = var > 0.f ? var : 0.f;
  float inv = rsqrtf(var + 1e-5f);
  float cr = crit[n];
  float r0 = h[n*128 + c0], r1 = h[n*128 + c1];
  o0 = (o0-mu)*inv*lng[c0] + lnb[c0] + cr + r0;
  o1 = (o1-mu)*inv*lng[c1] + lnb[c1] + cr + r1;
  h[n*128 + c0] = o0; h[n*128 + c1] = o1;
}

// ---------------- pooling: one block per graph, atomic-free ----------------
__global__ __launch_bounds__(256) void k_pool(
    const float* __restrict__ h, float* __restrict__ gate,
    const int* __restrict__ start, float* __restrict__ out)
{
  __shared__ float red[4];
  __shared__ float sbc;
  __shared__ float4 accs[8][32];
  int b = blockIdx.x;
  int s0 = start[b], s1 = start[b+1];
  int tid = threadIdx.x, lane = tid & 63, wave = tid >> 6;
  float m = -3.0e38f;
  for (int i = s0 + tid; i < s1; i += 256) m = fmaxf(m, gate[i]);
  #pragma unroll
  for (int k = 1; k < 64; k <<= 1) m = fmaxf(m, __shfl_xor(m, k));
  if (lane == 0) red[wave] = m;
  __syncthreads();
  if (tid == 0) sbc = fmaxf(fmaxf(red[0],red[1]), fmaxf(red[2],red[3]));
  __syncthreads();
  float gm = sbc;
  __syncthreads();
  float s = 0.f;
  for (int i = s0 + tid; i < s1; i += 256){
    float p = __expf(gate[i] - gm);
    gate[i] = p;
    s += p;
  }
  #pragma unroll
  for (int k = 1; k < 64; k <<= 1) s += __shfl_xor(s, k);
  if (lane == 0) red[wave] = s;
  __syncthreads();
  if (tid == 0) sbc = red[0]+red[1]+red[2]+red[3];
  __syncthreads();
  float inv = 1.f / (sbc + 1e-16f);
  int c4 = (tid & 31) * 4;
  int g  = tid >> 5;
  float4 acc = make_float4(0.f,0.f,0.f,0.f);
  for (int i = s0 + g; i < s1; i += 8){
    float p = gate[i];
    float4 hv = *(const float4*)(h + i*128 + c4);
    acc.x = fmaf(p,hv.x,acc.x); acc.y = fmaf(p,hv.y,acc.y);
    acc.z = fmaf(p,hv.z,acc.z); acc.w = fmaf(p,hv.w,acc.w);
  }
  accs[g][tid & 31] = acc;
  __syncthreads();
  if (g == 0){
    float4 t = acc;
    #pragma unroll
    for (int k = 1; k < 8; k++){
      float4 o = accs[k][tid & 31];
      t.x += o.x; t.y += o.y; t.z += o.z; t.w += o.w;
    }
    t.x *= inv; t.y *= inv; t.z *= inv; t.w *= inv;
    *(float4*)(out + b*128 + c4) = t;
  }
}

extern "C" void kernel_launch(void* const* d_in, const int* in_sizes, int n_in,
                              void* d_out, int out_size, void* d_ws, size_t ws_size,
                              hipStream_t stream){
  (void)in_sizes; (void)n_in; (void)out_size; (void)ws_size;
  const float* x    = (const float*)d_in[0];
  const float* ea   = (const float*)d_in[1];
  const float* Win  = (const float*)d_in[2];
  const float* b_in = (const float*)d_in[3];
  const float* We1  = (const float*)d_in[4];
  const float* be1  = (const float*)d_in[5];
  const float* We2  = (const float*)d_in[6];
  const float* be2  = (const float*)d_in[7];
  const float* Wl   = (const float*)d_in[8];
  const float* a_src= (const float*)d_in[9];
  const float* a_dst= (const float*)d_in[10];
  const float* bl   = (const float*)d_in[11];
  const float* lng  = (const float*)d_in[12];
  const float* lnb  = (const float*)d_in[13];
  const float* Wg1  = (const float*)d_in[14];
  const float* bg1  = (const float*)d_in[15];
  const float* Wg2  = (const float*)d_in[16];
  const float* bg2  = (const float*)d_in[17];
  const int*   ei   = (const int*)d_in[18];
  const int*   batch= (const int*)d_in[19];
  float* out = (float*)d_out;

  char* w = (char*)d_ws;
  auto alloc = [&](size_t bytes){ char* p = w; w += (bytes + 255) & ~(size_t)255; return p; };
  float* h    = (float*)alloc((size_t)N_NODES*128*4);
  float* xp   = (float*)alloc((size_t)N_NODES*128*4);
  float* asn  = (float*)alloc((size_t)N_NODES*4*4);
  float* adn  = (float*)alloc((size_t)N_NODES*4*4);
  float* crit = (float*)alloc((size_t)N_NODES*4);
  int*   cnt  = (int*)alloc((size_t)N_NODES*4);
  int*   incl = (int*)alloc((size_t)N_NODES*4);
  int*   part = (int*)alloc(256*4);
  int*   pexc = (int*)alloc(256*4);
  int*   off  = (int*)alloc((size_t)(N_NODES+1)*4);
  int*   cur  = (int*)alloc((size_t)N_NODES*4);
  int*   csr  = (int*)alloc((size_t)N_EDGES*4);
  float* gate = (float*)alloc((size_t)N_NODES*4);
  int*   start= (int*)alloc((size_t)(N_B+1)*4);

  int nb_n = (N_NODES + 255)/256;   // 196
  int nb_e = (N_EDGES + 255)/256;   // 3125
  int nb_w = (N_NODES + 3)/4;       // 12500 (one wave per node)

  k_setup<<<nb_n,256,0,stream>>>(batch, start, crit, cnt);
  k_gemm<128,false,true,false><<<3125,256,0,stream>>>(x, Win, b_in, nullptr, nullptr, h,
                                                      nullptr, nullptr, nullptr, nullptr, nullptr);
  k_edge<<<nb_e,256,0,stream>>>(ea, We1, be1, We2, be2, ei, crit, cnt);
  k_scan1<<<nb_n,256,0,stream>>>(cnt, incl, part);
  k_scan2<<<1,256,0,stream>>>(part, pexc, nb_n);
  k_scan3<<<nb_n,256,0,stream>>>(cnt, incl, pexc, off, cur);
  k_fill<<<nb_e,256,0,stream>>>(ei, cur, csr);
  for (int l = 0; l < 4; l++){
    k_gemm<128,true,false,false><<<3125,256,0,stream>>>(h, Wl + (size_t)l*128*128, nullptr,
                                                        a_src + l*128, a_dst + l*128, xp, asn, adn,
                                                        nullptr, nullptr, nullptr);
    k_aggr<<<nb_w,256,0,stream>>>(xp, asn, adn, off, csr,
                                  bl + l*128, lng + l*128, lnb + l*128, crit, h);
  }
  k_gemm<64,false,true,true><<<1563,256,0,stream>>>(h, Wg1, bg1, nullptr, nullptr, nullptr,
                                                    nullptr, nullptr, Wg2, bg2, gate);
  k_pool<<<N_B,256,0,stream>>>(h, gate, start, out);
}

// Round 4
// 819.333 us; speedup vs baseline: 2.0831x; 1.0652x over previous
//
#include <hip/hip_runtime.h>
#include <math.h>

#define N_NODES 50000
#define N_EDGES 800000
#define N_B     64

__device__ __forceinline__ float lrelu(float x){ return x > 0.f ? x : 0.2f*x; }
__device__ __forceinline__ unsigned short f2b(float f){   // fp32 -> bf16 RNE
  unsigned u = __float_as_uint(f);
  return (unsigned short)((u + 0x7fffu + ((u >> 16) & 1u)) >> 16);
}
__device__ __forceinline__ float blo(unsigned u){ return __uint_as_float(u << 16); }
__device__ __forceinline__ float bhi(unsigned u){ return __uint_as_float(u & 0xffff0000u); }

// ---------------- setup: zero cnt + graph boundaries (batch sorted) ----------------
__global__ void k_setup(const int* __restrict__ batch, int* __restrict__ start,
                        int* __restrict__ cnt){
  int i = blockIdx.x*256 + threadIdx.x;
  if (i >= N_NODES) return;
  cnt[i] = 0;
  int b = batch[i];
  int bp = (i == 0) ? -1 : batch[i-1];
  for (int j = bp+1; j <= b; j++) start[j] = i;
  if (i == N_NODES-1){
    for (int j = b+1; j <= N_B; j++) start[j] = N_NODES;
  }
}

// ---------------- degree histogram (int atomic only) ----------------
__global__ void k_hist(const int* __restrict__ ei, int* __restrict__ cnt){
  int e = blockIdx.x*256 + threadIdx.x;
  if (e >= N_EDGES) return;
  atomicAdd(&cnt[ei[N_EDGES + e]], 1);
}

// ---------------- exclusive scan (3 kernels) ----------------
__global__ void k_scan1(const int* __restrict__ cnt, int* __restrict__ incl, int* __restrict__ part){
  __shared__ int sh[256];
  int tid = threadIdx.x, i = blockIdx.x*256 + tid;
  int v = (i < N_NODES) ? cnt[i] : 0;
  sh[tid] = v; __syncthreads();
  for (int off = 1; off < 256; off <<= 1){
    int t = (tid >= off) ? sh[tid-off] : 0;
    __syncthreads();
    sh[tid] += t; __syncthreads();
  }
  if (i < N_NODES) incl[i] = sh[tid];
  if (tid == 255) part[blockIdx.x] = sh[255];
}
__global__ void k_scan2(const int* __restrict__ part, int* __restrict__ pexcl, int nblocks){
  __shared__ int sh[256];
  int tid = threadIdx.x;
  int v = (tid < nblocks) ? part[tid] : 0;
  sh[tid] = v; __syncthreads();
  for (int off = 1; off < 256; off <<= 1){
    int t = (tid >= off) ? sh[tid-off] : 0;
    __syncthreads();
    sh[tid] += t; __syncthreads();
  }
  if (tid < nblocks) pexcl[tid] = sh[tid] - v;
}
__global__ void k_scan3(const int* __restrict__ cnt, const int* __restrict__ incl,
                        const int* __restrict__ pexcl, int* __restrict__ off, int* __restrict__ cur){
  int i = blockIdx.x*256 + threadIdx.x;
  if (i >= N_NODES) return;
  int e = incl[i] - cnt[i] + pexcl[i >> 8];
  off[i] = e; cur[i] = e;
  if (i == N_NODES-1) off[N_NODES] = e + cnt[i];
}

// ---------------- CSR fill + edge MLP scalar into CSR order ----------------
__global__ void k_fill(const float* __restrict__ ea, const float* __restrict__ We1,
                       const float* __restrict__ be1, const float* __restrict__ We2,
                       const float* __restrict__ be2, const int* __restrict__ ei,
                       int* __restrict__ cur, int* __restrict__ csr, float* __restrict__ sc){
  __shared__ float w0[16], w1[16], bb[16], w2s[16];
  __shared__ float b2s;
  int tid = threadIdx.x;
  if (tid < 16){
    w0[tid] = We1[tid]; w1[tid] = We1[16+tid]; bb[tid] = be1[tid];
    w2s[tid] = 0.25f*(We2[tid*4]+We2[tid*4+1]+We2[tid*4+2]+We2[tid*4+3]);
  }
  if (tid == 0) b2s = 0.25f*(be2[0]+be2[1]+be2[2]+be2[3]);
  __syncthreads();
  int e = blockIdx.x*256 + tid;
  if (e >= N_EDGES) return;
  float a0 = ea[2*e], a1 = ea[2*e+1];
  float s = b2s;
  #pragma unroll
  for (int j = 0; j < 16; j++){
    float v = fmaf(a0, w0[j], fmaf(a1, w1[j], bb[j]));
    v = v > 0.f ? v : 0.f;
    s = fmaf(v, w2s[j], s);
  }
  int d = ei[N_EDGES + e];
  int p = atomicAdd(&cur[d], 1);
  csr[p] = ei[e];        // src
  sc[p]  = s;            // edge scalar in CSR order
}

// ---------------- node GEMM: out = in[N,128] @ W[128,NC] (+bias)(+attn->bf16)(+gate) ----------------
template<int NC, bool ATTN, bool BIAS, bool GATE>
__global__ __launch_bounds__(256) void k_gemm(
    const float* __restrict__ in, const float* __restrict__ W,
    const float* __restrict__ bias, const float* __restrict__ a_s,
    const float* __restrict__ a_d, float* __restrict__ out,
    unsigned short* __restrict__ outb,
    float* __restrict__ asn, float* __restrict__ adn,
    const float* __restrict__ Wg2, const float* __restrict__ bg2,
    float* __restrict__ gate)
{
  constexpr int COLL = NC/4;      // 32 or 16 column-lanes
  constexpr int RG   = 64/COLL;   // 2 or 4 row groups
  constexpr int RPW  = 2*RG;      // rows per wave (2 accumulators)
  constexpr int RPB  = 4*RPW;     // rows per block
  __shared__ float hs[RPB][128];
  int tid = threadIdx.x;
  int wave = tid >> 6, lane = tid & 63;
  int cl = lane % COLL, rg = lane / COLL;
  int c4 = cl*4;
  for (int rbase = blockIdx.x*RPB; rbase < N_NODES; rbase += gridDim.x*RPB){
    __syncthreads();
    for (int i = tid; i < RPB*32; i += 256){
      int r = i >> 5, cc = (i & 31)*4;
      int gr = rbase + r;
      float4 v = make_float4(0.f,0.f,0.f,0.f);
      if (gr < N_NODES) v = *(const float4*)(in + gr*128 + cc);
      *(float4*)(&hs[r][cc]) = v;
    }
    __syncthreads();
    int r0 = wave*RPW + rg, r1 = r0 + RG;
    float ax=0,ay=0,az=0,aw=0, bx=0,by=0,bz=0,bw=0;
    #pragma unroll 4
    for (int k = 0; k < 128; k++){
      float4 w = *(const float4*)(W + k*NC + c4);
      float h0 = hs[r0][k], h1 = hs[r1][k];
      ax = fmaf(h0,w.x,ax); ay = fmaf(h0,w.y,ay); az = fmaf(h0,w.z,az); aw = fmaf(h0,w.w,aw);
      bx = fmaf(h1,w.x,bx); by = fmaf(h1,w.y,by); bz = fmaf(h1,w.z,bz); bw = fmaf(h1,w.w,bw);
    }
    int gr0 = rbase + r0, gr1 = rbase + r1;
    if (BIAS){
      float4 bv = *(const float4*)(bias + c4);
      ax += bv.x; ay += bv.y; az += bv.z; aw += bv.w;
      bx += bv.x; by += bv.y; bz += bv.z; bw += bv.w;
    }
    if (ATTN){
      int hh = c4 >> 5;
      float4 sa = *(const float4*)(a_s + c4);
      float4 da = *(const float4*)(a_d + c4);
      float pas0 = ax*sa.x + ay*sa.y + az*sa.z + aw*sa.w;
      float pad0 = ax*da.x + ay*da.y + az*da.z + aw*da.w;
      float pas1 = bx*sa.x + by*sa.y + bz*sa.z + bw*sa.w;
      float pad1 = bx*da.x + by*da.y + bz*da.z + bw*da.w;
      #pragma unroll
      for (int m = 1; m < 8; m <<= 1){
        pas0 += __shfl_xor(pas0, m); pad0 += __shfl_xor(pad0, m);
        pas1 += __shfl_xor(pas1, m); pad1 += __shfl_xor(pad1, m);
      }
      if ((lane & 7) == 0){
        if (gr0 < N_NODES){ asn[gr0*4+hh] = pas0; adn[gr0*4+hh] = pad0; }
        if (gr1 < N_NODES){ asn[gr1*4+hh] = pas1; adn[gr1*4+hh] = pad1; }
      }
    }
    if (GATE){
      float4 w2 = *(const float4*)(Wg2 + c4);
      float v0 = tanhf(ax)*w2.x + tanhf(ay)*w2.y + tanhf(az)*w2.z + tanhf(aw)*w2.w;
      float v1 = tanhf(bx)*w2.x + tanhf(by)*w2.y + tanhf(bz)*w2.z + tanhf(bw)*w2.w;
      #pragma unroll
      for (int m = 1; m < 16; m <<= 1){ v0 += __shfl_xor(v0, m); v1 += __shfl_xor(v1, m); }
      if (cl == 0){
        float b2 = bg2[0];
        if (gr0 < N_NODES) gate[gr0] = v0 + b2;
        if (gr1 < N_NODES) gate[gr1] = v1 + b2;
      }
    } else if (ATTN){
      if (gr0 < N_NODES){
        ushort4 pk; pk.x=f2b(ax); pk.y=f2b(ay); pk.z=f2b(az); pk.w=f2b(aw);
        *(ushort4*)(&outb[(size_t)gr0*128 + c4]) = pk;
      }
      if (gr1 < N_NODES){
        ushort4 pk; pk.x=f2b(bx); pk.y=f2b(by); pk.z=f2b(bz); pk.w=f2b(bw);
        *(ushort4*)(&outb[(size_t)gr1*128 + c4]) = pk;
      }
    } else {
      if (gr0 < N_NODES) *(float4*)(&out[gr0*NC + c4]) = make_float4(ax,ay,az,aw);
      if (gr1 < N_NODES) *(float4*)(&out[gr1*NC + c4]) = make_float4(bx,by,bz,bw);
    }
  }
}

// ---------------- per-node GAT softmax + aggregate + bias + LN + crit + residual ----------------
// v3: xp in bf16; lane covers channel pair (2l,2l+1) via one u32 gather; numerators in
// LDS at [edge*4+head] (b128 write, conflict-free 16-lane-broadcast read).
// CRIT: layer 0 also segment-sums sc -> crit[n]; later layers read crit[n].
template<bool CRIT>
__global__ __launch_bounds__(256) void k_aggr(
    const unsigned short* __restrict__ xpb, const float* __restrict__ asn,
    const float* __restrict__ adn, const int* __restrict__ off,
    const int* __restrict__ csr, const float* __restrict__ sc,
    const float* __restrict__ bl, const float* __restrict__ lng,
    const float* __restrict__ lnb, float* __restrict__ crit, float* __restrict__ h)
{
  __shared__ float lp[4][256];         // per-wave: [j*4 + head]
  int wave = threadIdx.x >> 6, lane = threadIdx.x & 63;
  int n = blockIdx.x*4 + wave;
  if (n >= N_NODES) return;            // waves independent, no __syncthreads
  int base = off[n], deg = off[n+1] - base;
  float4 ad4 = *(const float4*)(adn + n*4);
  float4 asf = *(const float4*)(asn + n*4);
  float ex = lrelu(asf.x+ad4.x), ey = lrelu(asf.y+ad4.y);
  float ez = lrelu(asf.z+ad4.z), ew = lrelu(asf.w+ad4.w);
  float mx = ex, my = ey, mz = ez, mw = ew;
  float cw = 0.f;
  // pass 1: lane-parallel max (+ crit segment sum)
  for (int j = lane; j < deg; j += 64){
    int s = csr[base + j];
    float4 a = *(const float4*)(asn + s*4);
    mx = fmaxf(mx, lrelu(a.x+ad4.x)); my = fmaxf(my, lrelu(a.y+ad4.y));
    mz = fmaxf(mz, lrelu(a.z+ad4.z)); mw = fmaxf(mw, lrelu(a.w+ad4.w));
    if (CRIT) cw += sc[base + j];
  }
  #pragma unroll
  for (int m = 1; m < 64; m <<= 1){
    mx = fmaxf(mx, __shfl_xor(mx, m)); my = fmaxf(my, __shfl_xor(my, m));
    mz = fmaxf(mz, __shfl_xor(mz, m)); mw = fmaxf(mw, __shfl_xor(mw, m));
    if (CRIT) cw += __shfl_xor(cw, m);
  }
  float cr;
  if (CRIT){ if (lane == 0) crit[n] = cw; cr = cw; }
  else cr = crit[n];
  // self-loop numerators (wave-uniform)
  float psx = __expf(ex-mx), psy = __expf(ey-my), psz = __expf(ez-mz), psw = __expf(ew-mw);
  int hh = lane >> 4;                               // head of this lane's channel pair
  float pself = hh < 2 ? (hh == 0 ? psx : psy) : (hh == 2 ? psz : psw);
  unsigned us = *(const unsigned*)(xpb + (size_t)n*128 + 2*lane);
  float acc0 = pself * blo(us), acc1 = pself * bhi(us);
  float sx = 0.f, sy = 0.f, sz = 0.f, sw = 0.f;     // lane-partial denominators
  float* myp = &lp[wave][0];
  // pass 2: 64-edge tiles
  for (int j0 = 0; j0 < deg; j0 += 64){
    int clen = deg - j0; if (clen > 64) clen = 64;
    float p0 = 0.f, p1 = 0.f, p2 = 0.f, p3 = 0.f;
    if (lane < clen){
      int s = csr[base + j0 + lane];
      float4 a = *(const float4*)(asn + s*4);
      p0 = __expf(lrelu(a.x+ad4.x)-mx);
      p1 = __expf(lrelu(a.y+ad4.y)-my);
      p2 = __expf(lrelu(a.z+ad4.z)-mz);
      p3 = __expf(lrelu(a.w+ad4.w)-mw);
      sx += p0; sy += p1; sz += p2; sw += p3;
    }
    *(float4*)(&myp[4*lane]) = make_float4(p0,p1,p2,p3);
    __threadfence_block();
    for (int c = 0; c < clen; c++){
      int s = csr[base + j0 + c];                   // wave-uniform
      float q = myp[4*c + hh];                      // 4 banks x 16-lane broadcast
      unsigned u = *(const unsigned*)(xpb + (size_t)s*128 + 2*lane);   // 256B/wave
      acc0 = fmaf(q, blo(u), acc0);
      acc1 = fmaf(q, bhi(u), acc1);
    }
    __threadfence_block();
  }
  #pragma unroll
  for (int m = 1; m < 64; m <<= 1){
    sx += __shfl_xor(sx, m); sy += __shfl_xor(sy, m);
    sz += __shfl_xor(sz, m); sw += __shfl_xor(sw, m);
  }
  sx += psx; sy += psy; sz += psz; sw += psw;
  float den = (hh < 2 ? (hh == 0 ? sx : sy) : (hh == 2 ? sz : sw)) + 1e-16f;
  float rden = 1.f / den;
  int c0 = 2*lane;
  float2 blv = *(const float2*)(bl + c0);
  float o0 = acc0*rden + blv.x;
  float o1 = acc1*rden + blv.y;
  // LayerNorm over 128 channels
  float su = o0 + o1, sq = o0*o0 + o1*o1;
  #pragma unroll
  for (int m = 1; m < 64; m <<= 1){ su += __shfl_xor(su, m); sq += __shfl_xor(sq, m); }
  float mu  = su * (1.f/128.f);
  float var = sq * (1.f/128.f) - mu*mu; var = var > 0.f ? var : 0.f;
  float inv = rsqrtf(var + 1e-5f);
  float2 rv  = *(const float2*)(h + (size_t)n*128 + c0);
  float2 gv  = *(const float2*)(lng + c0);
  float2 bv2 = *(const float2*)(lnb + c0);
  o0 = (o0-mu)*inv*gv.x + bv2.x + cr + rv.x;
  o1 = (o1-mu)*inv*gv.y + bv2.y + cr + rv.y;
  *(float2*)(&h[(size_t)n*128 + c0]) = make_float2(o0, o1);
}

// ---------------- pooling: one block per graph, atomic-free ----------------
__global__ __launch_bounds__(256) void k_pool(
    const float* __restrict__ h, float* __restrict__ gate,
    const int* __restrict__ start, float* __restrict__ out)
{
  __shared__ float red[4];
  __shared__ float sbc;
  __shared__ float4 accs[8][32];
  int b = blockIdx.x;
  int s0 = start[b], s1 = start[b+1];
  int tid = threadIdx.x, lane = tid & 63, wave = tid >> 6;
  float m = -3.0e38f;
  for (int i = s0 + tid; i < s1; i += 256) m = fmaxf(m, gate[i]);
  #pragma unroll
  for (int k = 1; k < 64; k <<= 1) m = fmaxf(m, __shfl_xor(m, k));
  if (lane == 0) red[wave] = m;
  __syncthreads();
  if (tid == 0) sbc = fmaxf(fmaxf(red[0],red[1]), fmaxf(red[2],red[3]));
  __syncthreads();
  float gm = sbc;
  __syncthreads();
  float s = 0.f;
  for (int i = s0 + tid; i < s1; i += 256){
    float p = __expf(gate[i] - gm);
    gate[i] = p;
    s += p;
  }
  #pragma unroll
  for (int k = 1; k < 64; k <<= 1) s += __shfl_xor(s, k);
  if (lane == 0) red[wave] = s;
  __syncthreads();
  if (tid == 0) sbc = red[0]+red[1]+red[2]+red[3];
  __syncthreads();
  float inv = 1.f / (sbc + 1e-16f);
  int c4 = (tid & 31) * 4;
  int g  = tid >> 5;
  float4 acc = make_float4(0.f,0.f,0.f,0.f);
  for (int i = s0 + g; i < s1; i += 8){
    float p = gate[i];
    float4 hv = *(const float4*)(h + (size_t)i*128 + c4);
    acc.x = fmaf(p,hv.x,acc.x); acc.y = fmaf(p,hv.y,acc.y);
    acc.z = fmaf(p,hv.z,acc.z); acc.w = fmaf(p,hv.w,acc.w);
  }
  accs[g][tid & 31] = acc;
  __syncthreads();
  if (g == 0){
    float4 t = acc;
    #pragma unroll
    for (int k = 1; k < 8; k++){
      float4 o = accs[k][tid & 31];
      t.x += o.x; t.y += o.y; t.z += o.z; t.w += o.w;
    }
    t.x *= inv; t.y *= inv; t.z *= inv; t.w *= inv;
    *(float4*)(out + b*128 + c4) = t;
  }
}

extern "C" void kernel_launch(void* const* d_in, const int* in_sizes, int n_in,
                              void* d_out, int out_size, void* d_ws, size_t ws_size,
                              hipStream_t stream){
  (void)in_sizes; (void)n_in; (void)out_size; (void)ws_size;
  const float* x    = (const float*)d_in[0];
  const float* ea   = (const float*)d_in[1];
  const float* Win  = (const float*)d_in[2];
  const float* b_in = (const float*)d_in[3];
  const float* We1  = (const float*)d_in[4];
  const float* be1  = (const float*)d_in[5];
  const float* We2  = (const float*)d_in[6];
  const float* be2  = (const float*)d_in[7];
  const float* Wl   = (const float*)d_in[8];
  const float* a_src= (const float*)d_in[9];
  const float* a_dst= (const float*)d_in[10];
  const float* bl   = (const float*)d_in[11];
  const float* lng  = (const float*)d_in[12];
  const float* lnb  = (const float*)d_in[13];
  const float* Wg1  = (const float*)d_in[14];
  const float* bg1  = (const float*)d_in[15];
  const float* Wg2  = (const float*)d_in[16];
  const float* bg2  = (const float*)d_in[17];
  const int*   ei   = (const int*)d_in[18];
  const int*   batch= (const int*)d_in[19];
  float* out = (float*)d_out;

  char* w = (char*)d_ws;
  auto alloc = [&](size_t bytes){ char* p = w; w += (bytes + 255) & ~(size_t)255; return p; };
  float* h    = (float*)alloc((size_t)N_NODES*128*4);
  unsigned short* xpb = (unsigned short*)alloc((size_t)N_NODES*128*2);
  float* asn  = (float*)alloc((size_t)N_NODES*4*4);
  float* adn  = (float*)alloc((size_t)N_NODES*4*4);
  float* crit = (float*)alloc((size_t)N_NODES*4);
  int*   cnt  = (int*)alloc((size_t)N_NODES*4);
  int*   incl = (int*)alloc((size_t)N_NODES*4);
  int*   part = (int*)alloc(256*4);
  int*   pexc = (int*)alloc(256*4);
  int*   off  = (int*)alloc((size_t)(N_NODES+1)*4);
  int*   cur  = (int*)alloc((size_t)N_NODES*4);
  int*   csr  = (int*)alloc((size_t)N_EDGES*4);
  float* sc   = (float*)alloc((size_t)N_EDGES*4);
  float* gate = (float*)alloc((size_t)N_NODES*4);
  int*   start= (int*)alloc((size_t)(N_B+1)*4);

  int nb_n = (N_NODES + 255)/256;   // 196
  int nb_e = (N_EDGES + 255)/256;   // 3125
  int nb_w = (N_NODES + 3)/4;       // 12500 (one wave per node)

  k_setup<<<nb_n,256,0,stream>>>(batch, start, cnt);
  k_gemm<128,false,true,false><<<3125,256,0,stream>>>(x, Win, b_in, nullptr, nullptr, h, nullptr,
                                                      nullptr, nullptr, nullptr, nullptr, nullptr);
  k_hist<<<nb_e,256,0,stream>>>(ei, cnt);
  k_scan1<<<nb_n,256,0,stream>>>(cnt, incl, part);
  k_scan2<<<1,256,0,stream>>>(part, pexc, nb_n);
  k_scan3<<<nb_n,256,0,stream>>>(cnt, incl, pexc, off, cur);
  k_fill<<<nb_e,256,0,stream>>>(ea, We1, be1, We2, be2, ei, cur, csr, sc);
  for (int l = 0; l < 4; l++){
    k_gemm<128,true,false,false><<<3125,256,0,stream>>>(h, Wl + (size_t)l*128*128, nullptr,
                                                        a_src + l*128, a_dst + l*128, nullptr, xpb,
                                                        asn, adn, nullptr, nullptr, nullptr);
    if (l == 0)
      k_aggr<true><<<nb_w,256,0,stream>>>(xpb, asn, adn, off, csr, sc,
                                          bl + l*128, lng + l*128, lnb + l*128, crit, h);
    else
      k_aggr<false><<<nb_w,256,0,stream>>>(xpb, asn, adn, off, csr, sc,
                                           bl + l*128, lng + l*128, lnb + l*128, crit, h);
  }
  k_gemm<64,false,true,true><<<1563,256,0,stream>>>(h, Wg1, bg1, nullptr, nullptr, nullptr, nullptr,
                                                    nullptr, nullptr, Wg2, bg2, gate);
  k_pool<<<N_B,256,0,stream>>>(h, gate, start, out);
}

// Round 5
// 625.128 us; speedup vs baseline: 2.7303x; 1.3107x over previous
//
#include <hip/hip_runtime.h>
#include <math.h>

#define N_NODES 50000
#define N_EDGES 800000
#define N_B     64

typedef __attribute__((ext_vector_type(8))) short v8s;
typedef __attribute__((ext_vector_type(4))) float v4f;

__device__ __forceinline__ float lrelu(float x){ return x > 0.f ? x : 0.2f*x; }
__device__ __forceinline__ unsigned short f2b(float f){   // fp32 -> bf16 RNE
  unsigned u = __float_as_uint(f);
  return (unsigned short)((u + 0x7fffu + ((u >> 16) & 1u)) >> 16);
}
__device__ __forceinline__ float blo(unsigned u){ return __uint_as_float(u << 16); }
__device__ __forceinline__ float bhi(unsigned u){ return __uint_as_float(u & 0xffff0000u); }

// ---------------- conversion: x->bf16, weights -> transposed bf16 (+fused attn cols) ----------------
// WlT layout per layer: [144][128] bf16, rows 0..127 = W^T, 128..131 = W·a_src (4 heads),
// 132..135 = W·a_dst, 136..143 = zero.
__global__ void k_conv(const float* __restrict__ x, const float* __restrict__ Win,
                       const float* __restrict__ Wl, const float* __restrict__ a_src,
                       const float* __restrict__ a_dst, const float* __restrict__ Wg1,
                       unsigned short* __restrict__ xb, unsigned short* __restrict__ WinT,
                       unsigned short* __restrict__ WlT, unsigned short* __restrict__ Wg1T){
  int i = blockIdx.x*256 + threadIdx.x;
  if (i < 1600000){                                   // xb: 6.4M floats via float4
    float4 v = ((const float4*)x)[i];
    ushort4 p; p.x=f2b(v.x); p.y=f2b(v.y); p.z=f2b(v.z); p.w=f2b(v.w);
    ((ushort4*)xb)[i] = p;
    return;
  }
  i -= 1600000;
  if (i < 16384){                                     // WinT[n][k] = Win[k][n]
    int n = i >> 7, k = i & 127;
    WinT[n*128+k] = f2b(Win[k*128+n]);
    return;
  }
  i -= 16384;
  if (i < 65536){                                     // WlT main
    int l = i >> 14, n = (i >> 7) & 127, k = i & 127;
    WlT[l*144*128 + n*128 + k] = f2b(Wl[l*16384 + k*128 + n]);
    return;
  }
  i -= 65536;
  if (i < 4096){                                      // fused attn cols
    int l = i >> 10, k = (i >> 3) & 127, t = i & 7;
    int hh = t & 3, sd = t >> 2;
    const float* av = (sd ? a_dst : a_src) + l*128 + hh*32;
    const float* wr = Wl + l*16384 + k*128 + hh*32;
    float s = 0.f;
    #pragma unroll
    for (int c = 0; c < 32; c++) s = fmaf(wr[c], av[c], s);
    WlT[l*144*128 + (128 + sd*4 + hh)*128 + k] = f2b(s);
    return;
  }
  i -= 4096;
  if (i < 4096){                                      // zero rows 136..143
    int l = i >> 10, r = (i >> 7) & 7, k = i & 127;
    WlT[l*144*128 + (136+r)*128 + k] = 0;
    return;
  }
  i -= 4096;
  if (i < 8192){                                      // Wg1T[n][k] = Wg1[k][n], n<64
    int n = i >> 7, k = i & 127;
    Wg1T[n*128+k] = f2b(Wg1[k*64+n]);
  }
}

// ---------------- setup: zero cnt + graph boundaries (batch sorted) ----------------
__global__ void k_setup(const int* __restrict__ batch, int* __restrict__ start,
                        int* __restrict__ cnt){
  int i = blockIdx.x*256 + threadIdx.x;
  if (i >= N_NODES) return;
  cnt[i] = 0;
  int b = batch[i];
  int bp = (i == 0) ? -1 : batch[i-1];
  for (int j = bp+1; j <= b; j++) start[j] = i;
  if (i == N_NODES-1){
    for (int j = b+1; j <= N_B; j++) start[j] = N_NODES;
  }
}

// ---------------- degree histogram: 4 edges/thread, 4 atomics in flight ----------------
__global__ void k_hist(const int* __restrict__ ei, int* __restrict__ cnt){
  int t = blockIdx.x*256 + threadIdx.x;
  if (t >= 200000) return;
  int d0 = ei[N_EDGES + t];
  int d1 = ei[N_EDGES + t + 200000];
  int d2 = ei[N_EDGES + t + 400000];
  int d3 = ei[N_EDGES + t + 600000];
  atomicAdd(&cnt[d0], 1); atomicAdd(&cnt[d1], 1);
  atomicAdd(&cnt[d2], 1); atomicAdd(&cnt[d3], 1);
}

// ---------------- exclusive scan (3 kernels) ----------------
__global__ void k_scan1(const int* __restrict__ cnt, int* __restrict__ incl, int* __restrict__ part){
  __shared__ int sh[256];
  int tid = threadIdx.x, i = blockIdx.x*256 + tid;
  int v = (i < N_NODES) ? cnt[i] : 0;
  sh[tid] = v; __syncthreads();
  for (int off = 1; off < 256; off <<= 1){
    int t = (tid >= off) ? sh[tid-off] : 0;
    __syncthreads();
    sh[tid] += t; __syncthreads();
  }
  if (i < N_NODES) incl[i] = sh[tid];
  if (tid == 255) part[blockIdx.x] = sh[255];
}
__global__ void k_scan2(const int* __restrict__ part, int* __restrict__ pexcl, int nblocks){
  __shared__ int sh[256];
  int tid = threadIdx.x;
  int v = (tid < nblocks) ? part[tid] : 0;
  sh[tid] = v; __syncthreads();
  for (int off = 1; off < 256; off <<= 1){
    int t = (tid >= off) ? sh[tid-off] : 0;
    __syncthreads();
    sh[tid] += t; __syncthreads();
  }
  if (tid < nblocks) pexcl[tid] = sh[tid] - v;
}
__global__ void k_scan3(const int* __restrict__ cnt, const int* __restrict__ incl,
                        const int* __restrict__ pexcl, int* __restrict__ off, int* __restrict__ cur){
  int i = blockIdx.x*256 + threadIdx.x;
  if (i >= N_NODES) return;
  int e = incl[i] - cnt[i] + pexcl[i >> 8];
  off[i] = e; cur[i] = e;
  if (i == N_NODES-1) off[N_NODES] = e + cnt[i];
}

// ---------------- CSR fill + edge MLP scalar, 4 edges/thread ----------------
__global__ void k_fill(const float* __restrict__ ea, const float* __restrict__ We1,
                       const float* __restrict__ be1, const float* __restrict__ We2,
                       const float* __restrict__ be2, const int* __restrict__ ei,
                       int* __restrict__ cur, int* __restrict__ csr, float* __restrict__ sc){
  __shared__ float w0[16], w1[16], bb[16], w2s[16];
  __shared__ float b2s;
  int tid = threadIdx.x;
  if (tid < 16){
    w0[tid] = We1[tid]; w1[tid] = We1[16+tid]; bb[tid] = be1[tid];
    w2s[tid] = 0.25f*(We2[tid*4]+We2[tid*4+1]+We2[tid*4+2]+We2[tid*4+3]);
  }
  if (tid == 0) b2s = 0.25f*(be2[0]+be2[1]+be2[2]+be2[3]);
  __syncthreads();
  int t = blockIdx.x*256 + tid;
  if (t >= 200000) return;
  #pragma unroll
  for (int r = 0; r < 4; r++){
    int e = t + r*200000;
    float a0 = ea[2*e], a1 = ea[2*e+1];
    float s = b2s;
    #pragma unroll
    for (int j = 0; j < 16; j++){
      float v = fmaf(a0, w0[j], fmaf(a1, w1[j], bb[j]));
      v = v > 0.f ? v : 0.f;
      s = fmaf(v, w2s[j], s);
    }
    int d = ei[N_EDGES + e];
    int p = atomicAdd(&cur[d], 1);
    csr[p] = ei[e];
    sc[p]  = s;
  }
}

// ---------------- MFMA GEMM: C[N,NT*16] = A[N,128](bf16) @ Bt^T (bf16), fp32 accum ----------------
// MODE 0: +bias -> h fp32 + hb bf16.   MODE 1: cols 0..127 -> xpb bf16; col-tile 8 = asn/adn.
// MODE 2 (NT=4): gate[r] = sum_c tanh(o+bg1)*Wg2 + bg2.
template<int NT, int MODE>
__global__ __launch_bounds__(256) void k_mgemm(
    const unsigned short* __restrict__ A, const unsigned short* __restrict__ Bt,
    const float* __restrict__ bias,
    float* __restrict__ h, unsigned short* __restrict__ hb,
    unsigned short* __restrict__ xpb, float* __restrict__ asn, float* __restrict__ adn,
    const float* __restrict__ Wg2, const float* __restrict__ bg2, float* __restrict__ gate)
{
  __shared__ __attribute__((aligned(16))) unsigned short Bs[NT*16][136];
  __shared__ __attribute__((aligned(16))) unsigned short As[4][16][136];
  int tid = threadIdx.x, wave = tid >> 6, lane = tid & 63;
  int l15 = lane & 15, quad = lane >> 4;
  int rbase = blockIdx.x * 64;
  for (int id = tid; id < NT*16*16; id += 256){
    int r = id >> 4, ch = id & 15;
    *(v8s*)&Bs[r][ch*8] = *(const v8s*)(Bt + r*128 + ch*8);
  }
  for (int id = tid; id < 64*16; id += 256){
    int r = id >> 4, ch = id & 15;
    int gr = rbase + r;
    v8s v = {0,0,0,0,0,0,0,0};
    if (gr < N_NODES) v = *(const v8s*)(A + (size_t)gr*128 + ch*8);
    *(v8s*)&As[r >> 4][r & 15][ch*8] = v;
  }
  __syncthreads();
  v4f acc[NT];
  #pragma unroll
  for (int t = 0; t < NT; t++) acc[t] = (v4f){0.f,0.f,0.f,0.f};
  #pragma unroll
  for (int kb = 0; kb < 4; kb++){
    v8s a = *(v8s*)&As[wave][l15][kb*32 + quad*8];
    #pragma unroll
    for (int ct = 0; ct < NT; ct++){
      v8s b = *(v8s*)&Bs[ct*16 + l15][kb*32 + quad*8];
      acc[ct] = __builtin_amdgcn_mfma_f32_16x16x32_bf16(a, b, acc[ct], 0, 0, 0);
    }
  }
  int row0 = rbase + wave*16 + quad*4;     // rows row0..row0+3 held in acc[.][r]
  if (MODE == 0){
    #pragma unroll
    for (int ct = 0; ct < 8; ct++){
      float bcol = bias[ct*16 + l15];
      #pragma unroll
      for (int r = 0; r < 4; r++){
        int gr = row0 + r;
        if (gr < N_NODES){
          float v = acc[ct][r] + bcol;
          h[(size_t)gr*128 + ct*16 + l15] = v;
          hb[(size_t)gr*128 + ct*16 + l15] = f2b(v);
        }
      }
    }
  } else if (MODE == 1){
    #pragma unroll
    for (int ct = 0; ct < 8; ct++){
      #pragma unroll
      for (int r = 0; r < 4; r++){
        int gr = row0 + r;
        if (gr < N_NODES) xpb[(size_t)gr*128 + ct*16 + l15] = f2b(acc[ct][r]);
      }
    }
    #pragma unroll
    for (int r = 0; r < 4; r++){
      int gr = row0 + r;
      if (gr < N_NODES){
        float v = acc[NT-1][r];
        if (l15 < 4) asn[gr*4 + l15] = v;
        else if (l15 < 8) adn[gr*4 + (l15-4)] = v;
      }
    }
  } else {
    float part[4] = {0.f,0.f,0.f,0.f};
    #pragma unroll
    for (int ct = 0; ct < NT; ct++){
      float b1 = bias[ct*16 + l15];
      float w2 = Wg2[ct*16 + l15];
      #pragma unroll
      for (int r = 0; r < 4; r++) part[r] = fmaf(tanhf(acc[ct][r] + b1), w2, part[r]);
    }
    #pragma unroll
    for (int m = 1; m < 16; m <<= 1){
      #pragma unroll
      for (int r = 0; r < 4; r++) part[r] += __shfl_xor(part[r], m);
    }
    if (l15 == 0){
      float b2 = bg2[0];
      #pragma unroll
      for (int r = 0; r < 4; r++){
        int gr = row0 + r;
        if (gr < N_NODES) gate[gr] = part[r] + b2;
      }
    }
  }
}

// ---------------- per-node GAT softmax + aggregate + bias + LN + crit + residual ----------------
// v4: shfl-broadcast src index (no csr reload), 32-bit gather addressing, 1-deep pipeline.
template<bool CRIT>
__global__ __launch_bounds__(256) void k_aggr(
    const unsigned short* __restrict__ xpb, const float* __restrict__ asn,
    const float* __restrict__ adn, const int* __restrict__ off,
    const int* __restrict__ csr, const float* __restrict__ sc,
    const float* __restrict__ bl, const float* __restrict__ lng,
    const float* __restrict__ lnb, float* __restrict__ crit,
    float* __restrict__ h, unsigned short* __restrict__ hb)
{
  __shared__ float lp[4][256];
  int wave = threadIdx.x >> 6, lane = threadIdx.x & 63;
  int n = blockIdx.x*4 + wave;
  if (n >= N_NODES) return;
  int base = off[n], deg = off[n+1] - base;
  float4 ad4 = *(const float4*)(adn + n*4);
  float4 asf = *(const float4*)(asn + n*4);
  float ex = lrelu(asf.x+ad4.x), ey = lrelu(asf.y+ad4.y);
  float ez = lrelu(asf.z+ad4.z), ew = lrelu(asf.w+ad4.w);
  float mx = ex, my = ey, mz = ez, mw = ew;
  float cw = 0.f;
  for (int j = lane; j < deg; j += 64){
    int s = csr[base + j];
    float4 a = *(const float4*)(asn + s*4);
    mx = fmaxf(mx, lrelu(a.x+ad4.x)); my = fmaxf(my, lrelu(a.y+ad4.y));
    mz = fmaxf(mz, lrelu(a.z+ad4.z)); mw = fmaxf(mw, lrelu(a.w+ad4.w));
    if (CRIT) cw += sc[base + j];
  }
  #pragma unroll
  for (int m = 1; m < 64; m <<= 1){
    mx = fmaxf(mx, __shfl_xor(mx, m)); my = fmaxf(my, __shfl_xor(my, m));
    mz = fmaxf(mz, __shfl_xor(mz, m)); mw = fmaxf(mw, __shfl_xor(mw, m));
    if (CRIT) cw += __shfl_xor(cw, m);
  }
  float cr;
  if (CRIT){ if (lane == 0) crit[n] = cw; cr = cw; }
  else cr = crit[n];
  float psx = __expf(ex-mx), psy = __expf(ey-my), psz = __expf(ez-mz), psw = __expf(ew-mw);
  int hh = lane >> 4;
  float pself = hh < 2 ? (hh == 0 ? psx : psy) : (hh == 2 ? psz : psw);
  const unsigned* xw = (const unsigned*)xpb;
  unsigned us = xw[(unsigned)n*64u + lane];
  float acc0 = pself * blo(us), acc1 = pself * bhi(us);
  float sx = 0.f, sy = 0.f, sz = 0.f, sw = 0.f;
  float* myp = &lp[wave][0];
  for (int j0 = 0; j0 < deg; j0 += 64){
    int clen = deg - j0; if (clen > 64) clen = 64;
    int sreg = 0;
    float p0 = 0.f, p1 = 0.f, p2 = 0.f, p3 = 0.f;
    if (lane < clen){
      sreg = csr[base + j0 + lane];
      float4 a = *(const float4*)(asn + sreg*4);
      p0 = __expf(lrelu(a.x+ad4.x)-mx);
      p1 = __expf(lrelu(a.y+ad4.y)-my);
      p2 = __expf(lrelu(a.z+ad4.z)-mz);
      p3 = __expf(lrelu(a.w+ad4.w)-mw);
      sx += p0; sy += p1; sz += p2; sw += p3;
    }
    *(float4*)(&myp[4*lane]) = make_float4(p0,p1,p2,p3);
    __threadfence_block();
    int s0 = __shfl(sreg, 0);
    unsigned u = xw[(unsigned)s0*64u + lane];
    for (int c = 0; c < clen-1; c++){
      float q = myp[4*c + hh];
      int sn = __shfl(sreg, c+1);
      unsigned un = xw[(unsigned)sn*64u + lane];
      acc0 = fmaf(q, blo(u), acc0);
      acc1 = fmaf(q, bhi(u), acc1);
      u = un;
    }
    float q = myp[4*(clen-1) + hh];
    acc0 = fmaf(q, blo(u), acc0);
    acc1 = fmaf(q, bhi(u), acc1);
    __threadfence_block();
  }
  #pragma unroll
  for (int m = 1; m < 64; m <<= 1){
    sx += __shfl_xor(sx, m); sy += __shfl_xor(sy, m);
    sz += __shfl_xor(sz, m); sw += __shfl_xor(sw, m);
  }
  sx += psx; sy += psy; sz += psz; sw += psw;
  float den = (hh < 2 ? (hh == 0 ? sx : sy) : (hh == 2 ? sz : sw)) + 1e-16f;
  float rden = 1.f / den;
  int c0 = 2*lane;
  float2 blv = *(const float2*)(bl + c0);
  float o0 = acc0*rden + blv.x;
  float o1 = acc1*rden + blv.y;
  float su = o0 + o1, sq = o0*o0 + o1*o1;
  #pragma unroll
  for (int m = 1; m < 64; m <<= 1){ su += __shfl_xor(su, m); sq += __shfl_xor(sq, m); }
  float mu  = su * (1.f/128.f);
  float var = sq * (1.f/128.f) - mu*mu; var = var > 0.f ? var : 0.f;
  float inv = rsqrtf(var + 1e-5f);
  float2 rv  = *(const float2*)(h + (size_t)n*128 + c0);
  float2 gv  = *(const float2*)(lng + c0);
  float2 bv2 = *(const float2*)(lnb + c0);
  o0 = (o0-mu)*inv*gv.x + bv2.x + cr + rv.x;
  o1 = (o1-mu)*inv*gv.y + bv2.y + cr + rv.y;
  *(float2*)(&h[(size_t)n*128 + c0]) = make_float2(o0, o1);
  *(unsigned*)(&hb[(size_t)n*128 + c0]) = ((unsigned)f2b(o1) << 16) | f2b(o0);
}

// ---------------- pooling: one block per graph, atomic-free ----------------
__global__ __launch_bounds__(256) void k_pool(
    const float* __restrict__ h, float* __restrict__ gate,
    const int* __restrict__ start, float* __restrict__ out)
{
  __shared__ float red[4];
  __shared__ float sbc;
  __shared__ float4 accs[8][32];
  int b = blockIdx.x;
  int s0 = start[b], s1 = start[b+1];
  int tid = threadIdx.x, lane = tid & 63, wave = tid >> 6;
  float m = -3.0e38f;
  for (int i = s0 + tid; i < s1; i += 256) m = fmaxf(m, gate[i]);
  #pragma unroll
  for (int k = 1; k < 64; k <<= 1) m = fmaxf(m, __shfl_xor(m, k));
  if (lane == 0) red[wave] = m;
  __syncthreads();
  if (tid == 0) sbc = fmaxf(fmaxf(red[0],red[1]), fmaxf(red[2],red[3]));
  __syncthreads();
  float gm = sbc;
  __syncthreads();
  float s = 0.f;
  for (int i = s0 + tid; i < s1; i += 256){
    float p = __expf(gate[i] - gm);
    gate[i] = p;
    s += p;
  }
  #pragma unroll
  for (int k = 1; k < 64; k <<= 1) s += __shfl_xor(s, k);
  if (lane == 0) red[wave] = s;
  __syncthreads();
  if (tid == 0) sbc = red[0]+red[1]+red[2]+red[3];
  __syncthreads();
  float inv = 1.f / (sbc + 1e-16f);
  int c4 = (tid & 31) * 4;
  int g  = tid >> 5;
  float4 acc = make_float4(0.f,0.f,0.f,0.f);
  for (int i = s0 + g; i < s1; i += 8){
    float p = gate[i];
    float4 hv = *(const float4*)(h + (size_t)i*128 + c4);
    acc.x = fmaf(p,hv.x,acc.x); acc.y = fmaf(p,hv.y,acc.y);
    acc.z = fmaf(p,hv.z,acc.z); acc.w = fmaf(p,hv.w,acc.w);
  }
  accs[g][tid & 31] = acc;
  __syncthreads();
  if (g == 0){
    float4 t = acc;
    #pragma unroll
    for (int k = 1; k < 8; k++){
      float4 o = accs[k][tid & 31];
      t.x += o.x; t.y += o.y; t.z += o.z; t.w += o.w;
    }
    t.x *= inv; t.y *= inv; t.z *= inv; t.w *= inv;
    *(float4*)(out + b*128 + c4) = t;
  }
}

extern "C" void kernel_launch(void* const* d_in, const int* in_sizes, int n_in,
                              void* d_out, int out_size, void* d_ws, size_t ws_size,
                              hipStream_t stream){
  (void)in_sizes; (void)n_in; (void)out_size; (void)ws_size;
  const float* x    = (const float*)d_in[0];
  const float* ea   = (const float*)d_in[1];
  const float* Win  = (const float*)d_in[2];
  const float* b_in = (const float*)d_in[3];
  const float* We1  = (const float*)d_in[4];
  const float* be1  = (const float*)d_in[5];
  const float* We2  = (const float*)d_in[6];
  const float* be2  = (const float*)d_in[7];
  const float* Wl   = (const float*)d_in[8];
  const float* a_src= (const float*)d_in[9];
  const float* a_dst= (const float*)d_in[10];
  const float* bl   = (const float*)d_in[11];
  const float* lng  = (const float*)d_in[12];
  const float* lnb  = (const float*)d_in[13];
  const float* Wg1  = (const float*)d_in[14];
  const float* bg1  = (const float*)d_in[15];
  const float* Wg2  = (const float*)d_in[16];
  const float* bg2  = (const float*)d_in[17];
  const int*   ei   = (const int*)d_in[18];
  const int*   batch= (const int*)d_in[19];
  float* out = (float*)d_out;

  char* w = (char*)d_ws;
  auto alloc = [&](size_t bytes){ char* p = w; w += (bytes + 255) & ~(size_t)255; return p; };
  float* h    = (float*)alloc((size_t)N_NODES*128*4);
  unsigned short* hb  = (unsigned short*)alloc((size_t)N_NODES*128*2);
  unsigned short* xpb = (unsigned short*)alloc((size_t)N_NODES*128*2);  // also hosts xb pre-layers
  float* asn  = (float*)alloc((size_t)N_NODES*4*4);
  float* adn  = (float*)alloc((size_t)N_NODES*4*4);
  float* crit = (float*)alloc((size_t)N_NODES*4);
  int*   cnt  = (int*)alloc((size_t)N_NODES*4);
  int*   incl = (int*)alloc((size_t)N_NODES*4);
  int*   part = (int*)alloc(256*4);
  int*   pexc = (int*)alloc(256*4);
  int*   off  = (int*)alloc((size_t)(N_NODES+1)*4);
  int*   cur  = (int*)alloc((size_t)N_NODES*4);
  int*   csr  = (int*)alloc((size_t)N_EDGES*4);
  float* sc   = (float*)alloc((size_t)N_EDGES*4);
  float* gate = (float*)alloc((size_t)N_NODES*4);
  int*   start= (int*)alloc((size_t)(N_B+1)*4);
  unsigned short* WinT = (unsigned short*)alloc((size_t)128*128*2);
  unsigned short* WlT  = (unsigned short*)alloc((size_t)4*144*128*2);
  unsigned short* Wg1T = (unsigned short*)alloc((size_t)64*128*2);
  unsigned short* xb = xpb;

  int nb_n = (N_NODES + 255)/256;   // 196
  int nb_w = (N_NODES + 3)/4;       // 12500
  int nb_g = (N_NODES + 63)/64;     // 782
  int nb_c = (1698304 + 255)/256;   // 6634
  int nb_4e = (200000 + 255)/256;   // 782

  k_conv<<<nb_c,256,0,stream>>>(x, Win, Wl, a_src, a_dst, Wg1, xb, WinT, WlT, Wg1T);
  k_setup<<<nb_n,256,0,stream>>>(batch, start, cnt);
  k_hist<<<nb_4e,256,0,stream>>>(ei, cnt);
  k_mgemm<8,0><<<nb_g,256,0,stream>>>(xb, WinT, b_in, h, hb,
                                      nullptr, nullptr, nullptr, nullptr, nullptr, nullptr);
  k_scan1<<<nb_n,256,0,stream>>>(cnt, incl, part);
  k_scan2<<<1,256,0,stream>>>(part, pexc, nb_n);
  k_scan3<<<nb_n,256,0,stream>>>(cnt, incl, pexc, off, cur);
  k_fill<<<nb_4e,256,0,stream>>>(ea, We1, be1, We2, be2, ei, cur, csr, sc);
  for (int l = 0; l < 4; l++){
    k_mgemm<9,1><<<nb_g,256,0,stream>>>(hb, WlT + (size_t)l*144*128, nullptr, nullptr, nullptr,
                                        xpb, asn, adn, nullptr, nullptr, nullptr);
    if (l == 0)
      k_aggr<true><<<nb_w,256,0,stream>>>(xpb, asn, adn, off, csr, sc,
                                          bl + l*128, lng + l*128, lnb + l*128, crit, h, hb);
    else
      k_aggr<false><<<nb_w,256,0,stream>>>(xpb, asn, adn, off, csr, sc,
                                           bl + l*128, lng + l*128, lnb + l*128, crit, h, hb);
  }
  k_mgemm<4,2><<<nb_g,256,0,stream>>>(hb, Wg1T, bg1, nullptr, nullptr,
                                      nullptr, nullptr, nullptr, Wg2, bg2, gate);
  k_pool<<<N_B,256,0,stream>>>(h, gate, start, out);
}

// Round 6
// 540.388 us; speedup vs baseline: 3.1584x; 1.1568x over previous
//
#include <hip/hip_runtime.h>
#include <math.h>

#define N_NODES 50000
#define N_EDGES 800000
#define N_B     64

typedef __attribute__((ext_vector_type(8))) short v8s;
typedef __attribute__((ext_vector_type(4))) float v4f;

__device__ __forceinline__ float lrelu(float x){ return x > 0.f ? x : 0.2f*x; }
__device__ __forceinline__ unsigned short f2b(float f){   // fp32 -> bf16 RNE
  unsigned u = __float_as_uint(f);
  return (unsigned short)((u + 0x7fffu + ((u >> 16) & 1u)) >> 16);
}
__device__ __forceinline__ float blo(unsigned u){ return __uint_as_float(u << 16); }
__device__ __forceinline__ float bhi(unsigned u){ return __uint_as_float(u & 0xffff0000u); }

// ---------------- conversion: x->bf16, weights -> transposed bf16 (+fused attn cols) ----------------
__global__ void k_conv(const float* __restrict__ x, const float* __restrict__ Win,
                       const float* __restrict__ Wl, const float* __restrict__ a_src,
                       const float* __restrict__ a_dst, const float* __restrict__ Wg1,
                       unsigned short* __restrict__ xb, unsigned short* __restrict__ WinT,
                       unsigned short* __restrict__ WlT, unsigned short* __restrict__ Wg1T){
  int i = blockIdx.x*256 + threadIdx.x;
  if (i < 1600000){
    float4 v = ((const float4*)x)[i];
    ushort4 p; p.x=f2b(v.x); p.y=f2b(v.y); p.z=f2b(v.z); p.w=f2b(v.w);
    ((ushort4*)xb)[i] = p;
    return;
  }
  i -= 1600000;
  if (i < 16384){
    int n = i >> 7, k = i & 127;
    WinT[n*128+k] = f2b(Win[k*128+n]);
    return;
  }
  i -= 16384;
  if (i < 65536){
    int l = i >> 14, n = (i >> 7) & 127, k = i & 127;
    WlT[l*144*128 + n*128 + k] = f2b(Wl[l*16384 + k*128 + n]);
    return;
  }
  i -= 65536;
  if (i < 4096){
    int l = i >> 10, k = (i >> 3) & 127, t = i & 7;
    int hh = t & 3, sd = t >> 2;
    const float* av = (sd ? a_dst : a_src) + l*128 + hh*32;
    const float* wr = Wl + l*16384 + k*128 + hh*32;
    float s = 0.f;
    #pragma unroll
    for (int c = 0; c < 32; c++) s = fmaf(wr[c], av[c], s);
    WlT[l*144*128 + (128 + sd*4 + hh)*128 + k] = f2b(s);
    return;
  }
  i -= 4096;
  if (i < 4096){
    int l = i >> 10, r = (i >> 7) & 7, k = i & 127;
    WlT[l*144*128 + (136+r)*128 + k] = 0;
    return;
  }
  i -= 4096;
  if (i < 8192){
    int n = i >> 7, k = i & 127;
    Wg1T[n*128+k] = f2b(Wg1[k*64+n]);
  }
}

// ---------------- setup: zero cnt + graph boundaries (batch sorted) ----------------
__global__ void k_setup(const int* __restrict__ batch, int* __restrict__ start,
                        int* __restrict__ cnt){
  int i = blockIdx.x*256 + threadIdx.x;
  if (i >= N_NODES) return;
  cnt[i] = 0;
  int b = batch[i];
  int bp = (i == 0) ? -1 : batch[i-1];
  for (int j = bp+1; j <= b; j++) start[j] = i;
  if (i == N_NODES-1){
    for (int j = b+1; j <= N_B; j++) start[j] = N_NODES;
  }
}

// ---------------- degree histogram + per-edge rank (atomic returns old count) ----------------
__global__ void k_hist(const int* __restrict__ ei, int* __restrict__ cnt, int* __restrict__ rank){
  int t = blockIdx.x*256 + threadIdx.x;
  if (t >= 200000) return;
  #pragma unroll
  for (int r = 0; r < 4; r++){
    int e = t + r*200000;
    int d = ei[N_EDGES + e];
    rank[e] = atomicAdd(&cnt[d], 1);
  }
}

// ---------------- exclusive scan (3 kernels) ----------------
__global__ void k_scan1(const int* __restrict__ cnt, int* __restrict__ incl, int* __restrict__ part){
  __shared__ int sh[256];
  int tid = threadIdx.x, i = blockIdx.x*256 + tid;
  int v = (i < N_NODES) ? cnt[i] : 0;
  sh[tid] = v; __syncthreads();
  for (int off = 1; off < 256; off <<= 1){
    int t = (tid >= off) ? sh[tid-off] : 0;
    __syncthreads();
    sh[tid] += t; __syncthreads();
  }
  if (i < N_NODES) incl[i] = sh[tid];
  if (tid == 255) part[blockIdx.x] = sh[255];
}
__global__ void k_scan2(const int* __restrict__ part, int* __restrict__ pexcl, int nblocks){
  __shared__ int sh[256];
  int tid = threadIdx.x;
  int v = (tid < nblocks) ? part[tid] : 0;
  sh[tid] = v; __syncthreads();
  for (int off = 1; off < 256; off <<= 1){
    int t = (tid >= off) ? sh[tid-off] : 0;
    __syncthreads();
    sh[tid] += t; __syncthreads();
  }
  if (tid < nblocks) pexcl[tid] = sh[tid] - v;
}
__global__ void k_scan3(const int* __restrict__ cnt, const int* __restrict__ incl,
                        const int* __restrict__ pexcl, int* __restrict__ off){
  int i = blockIdx.x*256 + threadIdx.x;
  if (i >= N_NODES) return;
  int e = incl[i] - cnt[i] + pexcl[i >> 8];
  off[i] = e;
  if (i == N_NODES-1) off[N_NODES] = e + cnt[i];
}

// ---------------- CSR fill + edge MLP scalar (atomic-free: p = off[d] + rank[e]) ----------------
__global__ void k_fill(const float* __restrict__ ea, const float* __restrict__ We1,
                       const float* __restrict__ be1, const float* __restrict__ We2,
                       const float* __restrict__ be2, const int* __restrict__ ei,
                       const int* __restrict__ off, const int* __restrict__ rank,
                       int* __restrict__ csr, float* __restrict__ sc){
  __shared__ float w0[16], w1[16], bb[16], w2s[16];
  __shared__ float b2s;
  int tid = threadIdx.x;
  if (tid < 16){
    w0[tid] = We1[tid]; w1[tid] = We1[16+tid]; bb[tid] = be1[tid];
    w2s[tid] = 0.25f*(We2[tid*4]+We2[tid*4+1]+We2[tid*4+2]+We2[tid*4+3]);
  }
  if (tid == 0) b2s = 0.25f*(be2[0]+be2[1]+be2[2]+be2[3]);
  __syncthreads();
  int t = blockIdx.x*256 + tid;
  if (t >= 200000) return;
  #pragma unroll
  for (int r = 0; r < 4; r++){
    int e = t + r*200000;
    float a0 = ea[2*e], a1 = ea[2*e+1];
    float s = b2s;
    #pragma unroll
    for (int j = 0; j < 16; j++){
      float v = fmaf(a0, w0[j], fmaf(a1, w1[j], bb[j]));
      v = v > 0.f ? v : 0.f;
      s = fmaf(v, w2s[j], s);
    }
    int d = ei[N_EDGES + e];
    int p = off[d] + rank[e];
    csr[p] = ei[e];
    sc[p]  = s;
  }
}

// ---------------- MFMA GEMM ----------------
template<int NT, int MODE>
__global__ __launch_bounds__(256) void k_mgemm(
    const unsigned short* __restrict__ A, const unsigned short* __restrict__ Bt,
    const float* __restrict__ bias,
    float* __restrict__ h, unsigned short* __restrict__ hb,
    unsigned short* __restrict__ xpb, float* __restrict__ asn, float* __restrict__ adn,
    const float* __restrict__ Wg2, const float* __restrict__ bg2, float* __restrict__ gate)
{
  __shared__ __attribute__((aligned(16))) unsigned short Bs[NT*16][136];
  __shared__ __attribute__((aligned(16))) unsigned short As[4][16][136];
  int tid = threadIdx.x, wave = tid >> 6, lane = tid & 63;
  int l15 = lane & 15, quad = lane >> 4;
  int rbase = blockIdx.x * 64;
  for (int id = tid; id < NT*16*16; id += 256){
    int r = id >> 4, ch = id & 15;
    *(v8s*)&Bs[r][ch*8] = *(const v8s*)(Bt + r*128 + ch*8);
  }
  for (int id = tid; id < 64*16; id += 256){
    int r = id >> 4, ch = id & 15;
    int gr = rbase + r;
    v8s v = {0,0,0,0,0,0,0,0};
    if (gr < N_NODES) v = *(const v8s*)(A + (size_t)gr*128 + ch*8);
    *(v8s*)&As[r >> 4][r & 15][ch*8] = v;
  }
  __syncthreads();
  v4f acc[NT];
  #pragma unroll
  for (int t = 0; t < NT; t++) acc[t] = (v4f){0.f,0.f,0.f,0.f};
  #pragma unroll
  for (int kb = 0; kb < 4; kb++){
    v8s a = *(v8s*)&As[wave][l15][kb*32 + quad*8];
    #pragma unroll
    for (int ct = 0; ct < NT; ct++){
      v8s b = *(v8s*)&Bs[ct*16 + l15][kb*32 + quad*8];
      acc[ct] = __builtin_amdgcn_mfma_f32_16x16x32_bf16(a, b, acc[ct], 0, 0, 0);
    }
  }
  int row0 = rbase + wave*16 + quad*4;
  if (MODE == 0){
    #pragma unroll
    for (int ct = 0; ct < 8; ct++){
      float bcol = bias[ct*16 + l15];
      #pragma unroll
      for (int r = 0; r < 4; r++){
        int gr = row0 + r;
        if (gr < N_NODES){
          float v = acc[ct][r] + bcol;
          h[(size_t)gr*128 + ct*16 + l15] = v;
          hb[(size_t)gr*128 + ct*16 + l15] = f2b(v);
        }
      }
    }
  } else if (MODE == 1){
    #pragma unroll
    for (int ct = 0; ct < 8; ct++){
      #pragma unroll
      for (int r = 0; r < 4; r++){
        int gr = row0 + r;
        if (gr < N_NODES) xpb[(size_t)gr*128 + ct*16 + l15] = f2b(acc[ct][r]);
      }
    }
    #pragma unroll
    for (int r = 0; r < 4; r++){
      int gr = row0 + r;
      if (gr < N_NODES){
        float v = acc[NT-1][r];
        if (l15 < 4) asn[gr*4 + l15] = v;
        else if (l15 < 8) adn[gr*4 + (l15-4)] = v;
      }
    }
  } else {
    float part[4] = {0.f,0.f,0.f,0.f};
    #pragma unroll
    for (int ct = 0; ct < NT; ct++){
      float b1 = bias[ct*16 + l15];
      float w2 = Wg2[ct*16 + l15];
      #pragma unroll
      for (int r = 0; r < 4; r++) part[r] = fmaf(tanhf(acc[ct][r] + b1), w2, part[r]);
    }
    #pragma unroll
    for (int m = 1; m < 16; m <<= 1){
      #pragma unroll
      for (int r = 0; r < 4; r++) part[r] += __shfl_xor(part[r], m);
    }
    if (l15 == 0){
      float b2 = bg2[0];
      #pragma unroll
      for (int r = 0; r < 4; r++){
        int gr = row0 + r;
        if (gr < N_NODES) gate[gr] = part[r] + b2;
      }
    }
  }
}

// ---------------- per-node GAT softmax + aggregate + bias + LN + crit + residual ----------------
// v5: deg<=64 fast path — single csr/asn gather feeds both max and numerators;
// inner loop: readlane -> SGPR base gather (scalar addressing), unroll x2.
template<bool CRIT>
__global__ __launch_bounds__(256) void k_aggr(
    const unsigned short* __restrict__ xpb, const float* __restrict__ asn,
    const float* __restrict__ adn, const int* __restrict__ off,
    const int* __restrict__ csr, const float* __restrict__ sc,
    const float* __restrict__ bl, const float* __restrict__ lng,
    const float* __restrict__ lnb, float* __restrict__ crit,
    float* __restrict__ h, unsigned short* __restrict__ hb)
{
  __shared__ float lp[4][256];
  int wave = threadIdx.x >> 6, lane = threadIdx.x & 63;
  int n = blockIdx.x*4 + wave;
  if (n >= N_NODES) return;
  int base = off[n], deg = off[n+1] - base;
  float4 ad4 = *(const float4*)(adn + n*4);
  float4 asf = *(const float4*)(asn + n*4);
  float ex = lrelu(asf.x+ad4.x), ey = lrelu(asf.y+ad4.y);
  float ez = lrelu(asf.z+ad4.z), ew = lrelu(asf.w+ad4.w);
  const unsigned* xw = (const unsigned*)xpb;
  float* myp = &lp[wave][0];
  int hh = lane >> 4;
  float acc0, acc1, sx, sy, sz, sw, cr;
  float psx, psy, psz, psw;

  if (deg <= 64){
    // ---- fast path: one gather serves max AND numerators ----
    int sreg = 0;
    float e0 = -3.0e38f, e1 = -3.0e38f, e2 = -3.0e38f, e3 = -3.0e38f;
    float cw = 0.f;
    if (lane < deg){
      sreg = csr[base + lane];
      float4 a = *(const float4*)(asn + sreg*4);
      e0 = lrelu(a.x+ad4.x); e1 = lrelu(a.y+ad4.y);
      e2 = lrelu(a.z+ad4.z); e3 = lrelu(a.w+ad4.w);
      if (CRIT) cw = sc[base + lane];
    }
    float mx = fmaxf(e0,ex), my = fmaxf(e1,ey), mz = fmaxf(e2,ez), mw = fmaxf(e3,ew);
    #pragma unroll
    for (int m = 1; m < 64; m <<= 1){
      mx = fmaxf(mx, __shfl_xor(mx, m)); my = fmaxf(my, __shfl_xor(my, m));
      mz = fmaxf(mz, __shfl_xor(mz, m)); mw = fmaxf(mw, __shfl_xor(mw, m));
      if (CRIT) cw += __shfl_xor(cw, m);
    }
    if (CRIT){ if (lane == 0) crit[n] = cw; cr = cw; }
    else cr = crit[n];
    psx = __expf(ex-mx); psy = __expf(ey-my); psz = __expf(ez-mz); psw = __expf(ew-mw);
    float p0 = 0.f, p1 = 0.f, p2 = 0.f, p3 = 0.f;
    if (lane < deg){
      p0 = __expf(e0-mx); p1 = __expf(e1-my); p2 = __expf(e2-mz); p3 = __expf(e3-mw);
    }
    sx = p0; sy = p1; sz = p2; sw = p3;
    *(float4*)(&myp[4*lane]) = make_float4(p0,p1,p2,p3);
    __threadfence_block();
    float pself = hh < 2 ? (hh == 0 ? psx : psy) : (hh == 2 ? psz : psw);
    unsigned us = (xw + ((size_t)(unsigned)n << 6))[lane];
    acc0 = pself * blo(us); acc1 = pself * bhi(us);
    int c = 0;
    for (; c + 1 < deg; c += 2){
      int s0 = __builtin_amdgcn_readlane(sreg, c);
      int s1 = __builtin_amdgcn_readlane(sreg, c+1);
      unsigned u0 = (xw + ((size_t)(unsigned)s0 << 6))[lane];   // SGPR base + lane*4
      unsigned u1 = (xw + ((size_t)(unsigned)s1 << 6))[lane];
      float q0 = myp[4*c + hh], q1 = myp[4*c + 4 + hh];
      acc0 = fmaf(q0, blo(u0), acc0); acc1 = fmaf(q0, bhi(u0), acc1);
      acc0 = fmaf(q1, blo(u1), acc0); acc1 = fmaf(q1, bhi(u1), acc1);
    }
    if (c < deg){
      int s0 = __builtin_amdgcn_readlane(sreg, c);
      unsigned u0 = (xw + ((size_t)(unsigned)s0 << 6))[lane];
      float q0 = myp[4*c + hh];
      acc0 = fmaf(q0, blo(u0), acc0); acc1 = fmaf(q0, bhi(u0), acc1);
    }
    __threadfence_block();
  } else {
    // ---- general path (rare): two-pass as before ----
    float mx = ex, my = ey, mz = ez, mw = ew;
    float cw = 0.f;
    for (int j = lane; j < deg; j += 64){
      int s = csr[base + j];
      float4 a = *(const float4*)(asn + s*4);
      mx = fmaxf(mx, lrelu(a.x+ad4.x)); my = fmaxf(my, lrelu(a.y+ad4.y));
      mz = fmaxf(mz, lrelu(a.z+ad4.z)); mw = fmaxf(mw, lrelu(a.w+ad4.w));
      if (CRIT) cw += sc[base + j];
    }
    #pragma unroll
    for (int m = 1; m < 64; m <<= 1){
      mx = fmaxf(mx, __shfl_xor(mx, m)); my = fmaxf(my, __shfl_xor(my, m));
      mz = fmaxf(mz, __shfl_xor(mz, m)); mw = fmaxf(mw, __shfl_xor(mw, m));
      if (CRIT) cw += __shfl_xor(cw, m);
    }
    if (CRIT){ if (lane == 0) crit[n] = cw; cr = cw; }
    else cr = crit[n];
    psx = __expf(ex-mx); psy = __expf(ey-my); psz = __expf(ez-mz); psw = __expf(ew-mw);
    float pself = hh < 2 ? (hh == 0 ? psx : psy) : (hh == 2 ? psz : psw);
    unsigned us = (xw + ((size_t)(unsigned)n << 6))[lane];
    acc0 = pself * blo(us); acc1 = pself * bhi(us);
    sx = 0.f; sy = 0.f; sz = 0.f; sw = 0.f;
    for (int j0 = 0; j0 < deg; j0 += 64){
      int clen = deg - j0; if (clen > 64) clen = 64;
      int sreg = 0;
      float p0 = 0.f, p1 = 0.f, p2 = 0.f, p3 = 0.f;
      if (lane < clen){
        sreg = csr[base + j0 + lane];
        float4 a = *(const float4*)(asn + sreg*4);
        p0 = __expf(lrelu(a.x+ad4.x)-mx);
        p1 = __expf(lrelu(a.y+ad4.y)-my);
        p2 = __expf(lrelu(a.z+ad4.z)-mz);
        p3 = __expf(lrelu(a.w+ad4.w)-mw);
        sx += p0; sy += p1; sz += p2; sw += p3;
      }
      *(float4*)(&myp[4*lane]) = make_float4(p0,p1,p2,p3);
      __threadfence_block();
      for (int c = 0; c < clen; c++){
        int s0 = __builtin_amdgcn_readlane(sreg, c);
        unsigned u = (xw + ((size_t)(unsigned)s0 << 6))[lane];
        float q = myp[4*c + hh];
        acc0 = fmaf(q, blo(u), acc0); acc1 = fmaf(q, bhi(u), acc1);
      }
      __threadfence_block();
    }
  }
  #pragma unroll
  for (int m = 1; m < 64; m <<= 1){
    sx += __shfl_xor(sx, m); sy += __shfl_xor(sy, m);
    sz += __shfl_xor(sz, m); sw += __shfl_xor(sw, m);
  }
  sx += psx; sy += psy; sz += psz; sw += psw;
  float den = (hh < 2 ? (hh == 0 ? sx : sy) : (hh == 2 ? sz : sw)) + 1e-16f;
  float rden = 1.f / den;
  int c0 = 2*lane;
  float2 blv = *(const float2*)(bl + c0);
  float o0 = acc0*rden + blv.x;
  float o1 = acc1*rden + blv.y;
  float su = o0 + o1, sq = o0*o0 + o1*o1;
  #pragma unroll
  for (int m = 1; m < 64; m <<= 1){ su += __shfl_xor(su, m); sq += __shfl_xor(sq, m); }
  float mu  = su * (1.f/128.f);
  float var = sq * (1.f/128.f) - mu*mu; var = var > 0.f ? var : 0.f;
  float inv = rsqrtf(var + 1e-5f);
  float2 rv  = *(const float2*)(h + (size_t)n*128 + c0);
  float2 gv  = *(const float2*)(lng + c0);
  float2 bv2 = *(const float2*)(lnb + c0);
  o0 = (o0-mu)*inv*gv.x + bv2.x + cr + rv.x;
  o1 = (o1-mu)*inv*gv.y + bv2.y + cr + rv.y;
  *(float2*)(&h[(size_t)n*128 + c0]) = make_float2(o0, o1);
  *(unsigned*)(&hb[(size_t)n*128 + c0]) = ((unsigned)f2b(o1) << 16) | f2b(o0);
}

// ---------------- pooling: one block per graph, atomic-free ----------------
__global__ __launch_bounds__(256) void k_pool(
    const float* __restrict__ h, float* __restrict__ gate,
    const int* __restrict__ start, float* __restrict__ out)
{
  __shared__ float red[4];
  __shared__ float sbc;
  __shared__ float4 accs[8][32];
  int b = blockIdx.x;
  int s0 = start[b], s1 = start[b+1];
  int tid = threadIdx.x, lane = tid & 63, wave = tid >> 6;
  float m = -3.0e38f;
  for (int i = s0 + tid; i < s1; i += 256) m = fmaxf(m, gate[i]);
  #pragma unroll
  for (int k = 1; k < 64; k <<= 1) m = fmaxf(m, __shfl_xor(m, k));
  if (lane == 0) red[wave] = m;
  __syncthreads();
  if (tid == 0) sbc = fmaxf(fmaxf(red[0],red[1]), fmaxf(red[2],red[3]));
  __syncthreads();
  float gm = sbc;
  __syncthreads();
  float s = 0.f;
  for (int i = s0 + tid; i < s1; i += 256){
    float p = __expf(gate[i] - gm);
    gate[i] = p;
    s += p;
  }
  #pragma unroll
  for (int k = 1; k < 64; k <<= 1) s += __shfl_xor(s, k);
  if (lane == 0) red[wave] = s;
  __syncthreads();
  if (tid == 0) sbc = red[0]+red[1]+red[2]+red[3];
  __syncthreads();
  float inv = 1.f / (sbc + 1e-16f);
  int c4 = (tid & 31) * 4;
  int g  = tid >> 5;
  float4 acc = make_float4(0.f,0.f,0.f,0.f);
  for (int i = s0 + g; i < s1; i += 8){
    float p = gate[i];
    float4 hv = *(const float4*)(h + (size_t)i*128 + c4);
    acc.x = fmaf(p,hv.x,acc.x); acc.y = fmaf(p,hv.y,acc.y);
    acc.z = fmaf(p,hv.z,acc.z); acc.w = fmaf(p,hv.w,acc.w);
  }
  accs[g][tid & 31] = acc;
  __syncthreads();
  if (g == 0){
    float4 t = acc;
    #pragma unroll
    for (int k = 1; k < 8; k++){
      float4 o = accs[k][tid & 31];
      t.x += o.x; t.y += o.y; t.z += o.z; t.w += o.w;
    }
    t.x *= inv; t.y *= inv; t.z *= inv; t.w *= inv;
    *(float4*)(out + b*128 + c4) = t;
  }
}

extern "C" void kernel_launch(void* const* d_in, const int* in_sizes, int n_in,
                              void* d_out, int out_size, void* d_ws, size_t ws_size,
                              hipStream_t stream){
  (void)in_sizes; (void)n_in; (void)out_size; (void)ws_size;
  const float* x    = (const float*)d_in[0];
  const float* ea   = (const float*)d_in[1];
  const float* Win  = (const float*)d_in[2];
  const float* b_in = (const float*)d_in[3];
  const float* We1  = (const float*)d_in[4];
  const float* be1  = (const float*)d_in[5];
  const float* We2  = (const float*)d_in[6];
  const float* be2  = (const float*)d_in[7];
  const float* Wl   = (const float*)d_in[8];
  const float* a_src= (const float*)d_in[9];
  const float* a_dst= (const float*)d_in[10];
  const float* bl   = (const float*)d_in[11];
  const float* lng  = (const float*)d_in[12];
  const float* lnb  = (const float*)d_in[13];
  const float* Wg1  = (const float*)d_in[14];
  const float* bg1  = (const float*)d_in[15];
  const float* Wg2  = (const float*)d_in[16];
  const float* bg2  = (const float*)d_in[17];
  const int*   ei   = (const int*)d_in[18];
  const int*   batch= (const int*)d_in[19];
  float* out = (float*)d_out;

  char* w = (char*)d_ws;
  auto alloc = [&](size_t bytes){ char* p = w; w += (bytes + 255) & ~(size_t)255; return p; };
  float* h    = (float*)alloc((size_t)N_NODES*128*4);
  unsigned short* hb  = (unsigned short*)alloc((size_t)N_NODES*128*2);
  unsigned short* xpb = (unsigned short*)alloc((size_t)N_NODES*128*2);  // also hosts xb pre-layers
  float* asn  = (float*)alloc((size_t)N_NODES*4*4);
  float* adn  = (float*)alloc((size_t)N_NODES*4*4);
  float* crit = (float*)alloc((size_t)N_NODES*4);
  int*   cnt  = (int*)alloc((size_t)N_NODES*4);
  int*   incl = (int*)alloc((size_t)N_NODES*4);
  int*   part = (int*)alloc(256*4);
  int*   pexc = (int*)alloc(256*4);
  int*   off  = (int*)alloc((size_t)(N_NODES+1)*4);
  int*   rank = (int*)alloc((size_t)N_EDGES*4);
  int*   csr  = (int*)alloc((size_t)N_EDGES*4);
  float* sc   = (float*)alloc((size_t)N_EDGES*4);
  float* gate = (float*)alloc((size_t)N_NODES*4);
  int*   start= (int*)alloc((size_t)(N_B+1)*4);
  unsigned short* WinT = (unsigned short*)alloc((size_t)128*128*2);
  unsigned short* WlT  = (unsigned short*)alloc((size_t)4*144*128*2);
  unsigned short* Wg1T = (unsigned short*)alloc((size_t)64*128*2);
  unsigned short* xb = xpb;

  int nb_n = (N_NODES + 255)/256;   // 196
  int nb_w = (N_NODES + 3)/4;       // 12500
  int nb_g = (N_NODES + 63)/64;     // 782
  int nb_c = (1698304 + 255)/256;   // 6634
  int nb_4e = (200000 + 255)/256;   // 782

  k_conv<<<nb_c,256,0,stream>>>(x, Win, Wl, a_src, a_dst, Wg1, xb, WinT, WlT, Wg1T);
  k_setup<<<nb_n,256,0,stream>>>(batch, start, cnt);
  k_hist<<<nb_4e,256,0,stream>>>(ei, cnt, rank);
  k_mgemm<8,0><<<nb_g,256,0,stream>>>(xb, WinT, b_in, h, hb,
                                      nullptr, nullptr, nullptr, nullptr, nullptr, nullptr);
  k_scan1<<<nb_n,256,0,stream>>>(cnt, incl, part);
  k_scan2<<<1,256,0,stream>>>(part, pexc, nb_n);
  k_scan3<<<nb_n,256,0,stream>>>(cnt, incl, pexc, off);
  k_fill<<<nb_4e,256,0,stream>>>(ea, We1, be1, We2, be2, ei, off, rank, csr, sc);
  for (int l = 0; l < 4; l++){
    k_mgemm<9,1><<<nb_g,256,0,stream>>>(hb, WlT + (size_t)l*144*128, nullptr, nullptr, nullptr,
                                        xpb, asn, adn, nullptr, nullptr, nullptr);
    if (l == 0)
      k_aggr<true><<<nb_w,256,0,stream>>>(xpb, asn, adn, off, csr, sc,
                                          bl + l*128, lng + l*128, lnb + l*128, crit, h, hb);
    else
      k_aggr<false><<<nb_w,256,0,stream>>>(xpb, asn, adn, off, csr, sc,
                                           bl + l*128, lng + l*128, lnb + l*128, crit, h, hb);
  }
  k_mgemm<4,2><<<nb_g,256,0,stream>>>(hb, Wg1T, bg1, nullptr, nullptr,
                                      nullptr, nullptr, nullptr, Wg2, bg2, gate);
  k_pool<<<N_B,256,0,stream>>>(h, gate, start, out);
}

// Round 7
// 482.413 us; speedup vs baseline: 3.5380x; 1.1202x over previous
//
#include <hip/hip_runtime.h>
#include <math.h>

#define N_NODES 50000
#define N_EDGES 800000
#define N_B     64

typedef __attribute__((ext_vector_type(8))) short v8s;
typedef __attribute__((ext_vector_type(4))) float v4f;

__device__ __forceinline__ float lrelu(float x){ return x > 0.f ? x : 0.2f*x; }
__device__ __forceinline__ unsigned short f2b(float f){   // fp32 -> bf16 RNE
  unsigned u = __float_as_uint(f);
  return (unsigned short)((u + 0x7fffu + ((u >> 16) & 1u)) >> 16);
}
__device__ __forceinline__ float blo(unsigned u){ return __uint_as_float(u << 16); }
__device__ __forceinline__ float bhi(unsigned u){ return __uint_as_float(u & 0xffff0000u); }

// ---------------- conversion: x->bf16, weights -> transposed bf16 (+fused attn cols) ----------------
__global__ void k_conv(const float* __restrict__ x, const float* __restrict__ Win,
                       const float* __restrict__ Wl, const float* __restrict__ a_src,
                       const float* __restrict__ a_dst, const float* __restrict__ Wg1,
                       unsigned short* __restrict__ xb, unsigned short* __restrict__ WinT,
                       unsigned short* __restrict__ WlT, unsigned short* __restrict__ Wg1T){
  int i = blockIdx.x*256 + threadIdx.x;
  if (i < 1600000){
    float4 v = ((const float4*)x)[i];
    ushort4 p; p.x=f2b(v.x); p.y=f2b(v.y); p.z=f2b(v.z); p.w=f2b(v.w);
    ((ushort4*)xb)[i] = p;
    return;
  }
  i -= 1600000;
  if (i < 16384){
    int n = i >> 7, k = i & 127;
    WinT[n*128+k] = f2b(Win[k*128+n]);
    return;
  }
  i -= 16384;
  if (i < 65536){
    int l = i >> 14, n = (i >> 7) & 127, k = i & 127;
    WlT[l*144*128 + n*128 + k] = f2b(Wl[l*16384 + k*128 + n]);
    return;
  }
  i -= 65536;
  if (i < 4096){
    int l = i >> 10, k = (i >> 3) & 127, t = i & 7;
    int hh = t & 3, sd = t >> 2;
    const float* av = (sd ? a_dst : a_src) + l*128 + hh*32;
    const float* wr = Wl + l*16384 + k*128 + hh*32;
    float s = 0.f;
    #pragma unroll
    for (int c = 0; c < 32; c++) s = fmaf(wr[c], av[c], s);
    WlT[l*144*128 + (128 + sd*4 + hh)*128 + k] = f2b(s);
    return;
  }
  i -= 4096;
  if (i < 4096){
    int l = i >> 10, r = (i >> 7) & 7, k = i & 127;
    WlT[l*144*128 + (136+r)*128 + k] = 0;
    return;
  }
  i -= 4096;
  if (i < 8192){
    int n = i >> 7, k = i & 127;
    Wg1T[n*128+k] = f2b(Wg1[k*64+n]);
  }
}

// ---------------- setup: zero cnt + graph boundaries (batch sorted) ----------------
__global__ void k_setup(const int* __restrict__ batch, int* __restrict__ start,
                        int* __restrict__ cnt){
  int i = blockIdx.x*256 + threadIdx.x;
  if (i >= N_NODES) return;
  cnt[i] = 0;
  int b = batch[i];
  int bp = (i == 0) ? -1 : batch[i-1];
  for (int j = bp+1; j <= b; j++) start[j] = i;
  if (i == N_NODES-1){
    for (int j = b+1; j <= N_B; j++) start[j] = N_NODES;
  }
}

// ---------------- degree histogram + per-edge rank (atomic returns old count) ----------------
__global__ void k_hist(const int* __restrict__ ei, int* __restrict__ cnt, int* __restrict__ rank){
  int t = blockIdx.x*256 + threadIdx.x;
  if (t >= 200000) return;
  #pragma unroll
  for (int r = 0; r < 4; r++){
    int e = t + r*200000;
    int d = ei[N_EDGES + e];
    rank[e] = atomicAdd(&cnt[d], 1);
  }
}

// ---------------- exclusive scan (3 kernels) ----------------
__global__ void k_scan1(const int* __restrict__ cnt, int* __restrict__ incl, int* __restrict__ part){
  __shared__ int sh[256];
  int tid = threadIdx.x, i = blockIdx.x*256 + tid;
  int v = (i < N_NODES) ? cnt[i] : 0;
  sh[tid] = v; __syncthreads();
  for (int off = 1; off < 256; off <<= 1){
    int t = (tid >= off) ? sh[tid-off] : 0;
    __syncthreads();
    sh[tid] += t; __syncthreads();
  }
  if (i < N_NODES) incl[i] = sh[tid];
  if (tid == 255) part[blockIdx.x] = sh[255];
}
__global__ void k_scan2(const int* __restrict__ part, int* __restrict__ pexcl, int nblocks){
  __shared__ int sh[256];
  int tid = threadIdx.x;
  int v = (tid < nblocks) ? part[tid] : 0;
  sh[tid] = v; __syncthreads();
  for (int off = 1; off < 256; off <<= 1){
    int t = (tid >= off) ? sh[tid-off] : 0;
    __syncthreads();
    sh[tid] += t; __syncthreads();
  }
  if (tid < nblocks) pexcl[tid] = sh[tid] - v;
}
__global__ void k_scan3(const int* __restrict__ cnt, const int* __restrict__ incl,
                        const int* __restrict__ pexcl, int* __restrict__ off){
  int i = blockIdx.x*256 + threadIdx.x;
  if (i >= N_NODES) return;
  int e = incl[i] - cnt[i] + pexcl[i >> 8];
  off[i] = e;
  if (i == N_NODES-1) off[N_NODES] = e + cnt[i];
}

// ---------------- CSR fill + edge MLP scalar (atomic-free, single 8B scatter) ----------------
__global__ void k_fill(const float* __restrict__ ea, const float* __restrict__ We1,
                       const float* __restrict__ be1, const float* __restrict__ We2,
                       const float* __restrict__ be2, const int* __restrict__ ei,
                       const int* __restrict__ off, const int* __restrict__ rank,
                       int2* __restrict__ es){
  __shared__ float w0[16], w1[16], bb[16], w2s[16];
  __shared__ float b2s;
  int tid = threadIdx.x;
  if (tid < 16){
    w0[tid] = We1[tid]; w1[tid] = We1[16+tid]; bb[tid] = be1[tid];
    w2s[tid] = 0.25f*(We2[tid*4]+We2[tid*4+1]+We2[tid*4+2]+We2[tid*4+3]);
  }
  if (tid == 0) b2s = 0.25f*(be2[0]+be2[1]+be2[2]+be2[3]);
  __syncthreads();
  int t = blockIdx.x*256 + tid;
  if (t >= 200000) return;
  #pragma unroll
  for (int r = 0; r < 4; r++){
    int e = t + r*200000;
    float a0 = ea[2*e], a1 = ea[2*e+1];
    float s = b2s;
    #pragma unroll
    for (int j = 0; j < 16; j++){
      float v = fmaf(a0, w0[j], fmaf(a1, w1[j], bb[j]));
      v = v > 0.f ? v : 0.f;
      s = fmaf(v, w2s[j], s);
    }
    int d = ei[N_EDGES + e];
    int p = off[d] + rank[e];
    es[p] = make_int2(ei[e], __float_as_int(s));
  }
}

// ---------------- MFMA GEMM ----------------
template<int NT, int MODE>
__global__ __launch_bounds__(256) void k_mgemm(
    const unsigned short* __restrict__ A, const unsigned short* __restrict__ Bt,
    const float* __restrict__ bias,
    float* __restrict__ h, unsigned short* __restrict__ hb,
    unsigned short* __restrict__ xpb, float* __restrict__ asn, float* __restrict__ adn,
    const float* __restrict__ Wg2, const float* __restrict__ bg2, float* __restrict__ gate)
{
  __shared__ __attribute__((aligned(16))) unsigned short Bs[NT*16][136];
  __shared__ __attribute__((aligned(16))) unsigned short As[4][16][136];
  int tid = threadIdx.x, wave = tid >> 6, lane = tid & 63;
  int l15 = lane & 15, quad = lane >> 4;
  int rbase = blockIdx.x * 64;
  for (int id = tid; id < NT*16*16; id += 256){
    int r = id >> 4, ch = id & 15;
    *(v8s*)&Bs[r][ch*8] = *(const v8s*)(Bt + r*128 + ch*8);
  }
  for (int id = tid; id < 64*16; id += 256){
    int r = id >> 4, ch = id & 15;
    int gr = rbase + r;
    v8s v = {0,0,0,0,0,0,0,0};
    if (gr < N_NODES) v = *(const v8s*)(A + (size_t)gr*128 + ch*8);
    *(v8s*)&As[r >> 4][r & 15][ch*8] = v;
  }
  __syncthreads();
  v4f acc[NT];
  #pragma unroll
  for (int t = 0; t < NT; t++) acc[t] = (v4f){0.f,0.f,0.f,0.f};
  #pragma unroll
  for (int kb = 0; kb < 4; kb++){
    v8s a = *(v8s*)&As[wave][l15][kb*32 + quad*8];
    #pragma unroll
    for (int ct = 0; ct < NT; ct++){
      v8s b = *(v8s*)&Bs[ct*16 + l15][kb*32 + quad*8];
      acc[ct] = __builtin_amdgcn_mfma_f32_16x16x32_bf16(a, b, acc[ct], 0, 0, 0);
    }
  }
  int row0 = rbase + wave*16 + quad*4;
  if (MODE == 0){
    #pragma unroll
    for (int ct = 0; ct < 8; ct++){
      float bcol = bias[ct*16 + l15];
      #pragma unroll
      for (int r = 0; r < 4; r++){
        int gr = row0 + r;
        if (gr < N_NODES){
          float v = acc[ct][r] + bcol;
          h[(size_t)gr*128 + ct*16 + l15] = v;
          hb[(size_t)gr*128 + ct*16 + l15] = f2b(v);
        }
      }
    }
  } else if (MODE == 1){
    #pragma unroll
    for (int ct = 0; ct < 8; ct++){
      #pragma unroll
      for (int r = 0; r < 4; r++){
        int gr = row0 + r;
        if (gr < N_NODES) xpb[(size_t)gr*128 + ct*16 + l15] = f2b(acc[ct][r]);
      }
    }
    #pragma unroll
    for (int r = 0; r < 4; r++){
      int gr = row0 + r;
      if (gr < N_NODES){
        float v = acc[NT-1][r];
        if (l15 < 4) asn[gr*4 + l15] = v;
        else if (l15 < 8) adn[gr*4 + (l15-4)] = v;
      }
    }
  } else {
    float part[4] = {0.f,0.f,0.f,0.f};
    #pragma unroll
    for (int ct = 0; ct < NT; ct++){
      float b1 = bias[ct*16 + l15];
      float w2 = Wg2[ct*16 + l15];
      #pragma unroll
      for (int r = 0; r < 4; r++) part[r] = fmaf(tanhf(acc[ct][r] + b1), w2, part[r]);
    }
    #pragma unroll
    for (int m = 1; m < 16; m <<= 1){
      #pragma unroll
      for (int r = 0; r < 4; r++) part[r] += __shfl_xor(part[r], m);
    }
    if (l15 == 0){
      float b2 = bg2[0];
      #pragma unroll
      for (int r = 0; r < 4; r++){
        int gr = row0 + r;
        if (gr < N_NODES) gate[gr] = part[r] + b2;
      }
    }
  }
}

// ---------------- per-node GAT softmax + aggregate + bias + LN + crit + residual ----------------
// v6: deg<=64 fast path with 8-deep branch-free gather pipeline (degR padding:
// lanes >= deg hold sreg=0 (valid addr) and wrote q=0 numerators, so padded
// iterations contribute exactly 0).
template<bool CRIT>
__global__ __launch_bounds__(256) void k_aggr(
    const unsigned short* __restrict__ xpb, const float* __restrict__ asn,
    const float* __restrict__ adn, const int* __restrict__ off,
    const int2* __restrict__ es,
    const float* __restrict__ bl, const float* __restrict__ lng,
    const float* __restrict__ lnb, float* __restrict__ crit,
    float* __restrict__ h, unsigned short* __restrict__ hb)
{
  __shared__ float lp[4][256];
  int wave = threadIdx.x >> 6, lane = threadIdx.x & 63;
  int n = blockIdx.x*4 + wave;
  if (n >= N_NODES) return;
  int base = off[n], deg = off[n+1] - base;
  float4 ad4 = *(const float4*)(adn + n*4);
  float4 asf = *(const float4*)(asn + n*4);
  float ex = lrelu(asf.x+ad4.x), ey = lrelu(asf.y+ad4.y);
  float ez = lrelu(asf.z+ad4.z), ew = lrelu(asf.w+ad4.w);
  const unsigned* xw = (const unsigned*)xpb;
  float* myp = &lp[wave][0];
  int hh = lane >> 4;
  float acc0, acc1, sx, sy, sz, sw, cr;
  float psx, psy, psz, psw;

  if (deg <= 64){
    int sreg = 0;
    float e0 = -3.0e38f, e1 = -3.0e38f, e2 = -3.0e38f, e3 = -3.0e38f;
    float cw = 0.f;
    if (lane < deg){
      int2 er = es[base + lane];
      sreg = er.x;
      float4 a = *(const float4*)(asn + sreg*4);
      e0 = lrelu(a.x+ad4.x); e1 = lrelu(a.y+ad4.y);
      e2 = lrelu(a.z+ad4.z); e3 = lrelu(a.w+ad4.w);
      if (CRIT) cw = __int_as_float(er.y);
    }
    float mx = fmaxf(e0,ex), my = fmaxf(e1,ey), mz = fmaxf(e2,ez), mw = fmaxf(e3,ew);
    #pragma unroll
    for (int m = 1; m < 64; m <<= 1){
      mx = fmaxf(mx, __shfl_xor(mx, m)); my = fmaxf(my, __shfl_xor(my, m));
      mz = fmaxf(mz, __shfl_xor(mz, m)); mw = fmaxf(mw, __shfl_xor(mw, m));
      if (CRIT) cw += __shfl_xor(cw, m);
    }
    if (CRIT){ if (lane == 0) crit[n] = cw; cr = cw; }
    else cr = crit[n];
    psx = __expf(ex-mx); psy = __expf(ey-my); psz = __expf(ez-mz); psw = __expf(ew-mw);
    float p0 = 0.f, p1 = 0.f, p2 = 0.f, p3 = 0.f;
    if (lane < deg){
      p0 = __expf(e0-mx); p1 = __expf(e1-my); p2 = __expf(e2-mz); p3 = __expf(e3-mw);
    }
    sx = p0; sy = p1; sz = p2; sw = p3;
    *(float4*)(&myp[4*lane]) = make_float4(p0,p1,p2,p3);
    __threadfence_block();
    float pself = hh < 2 ? (hh == 0 ? psx : psy) : (hh == 2 ? psz : psw);
    unsigned us = (xw + ((size_t)(unsigned)n << 6))[lane];
    acc0 = pself * blo(us); acc1 = pself * bhi(us);
    int degR = (deg + 7) & ~7;
    for (int c = 0; c < degR; c += 8){
      unsigned u[8];
      #pragma unroll
      for (int k = 0; k < 8; k++){
        int s0 = __builtin_amdgcn_readlane(sreg, c + k);
        u[k] = (xw + ((size_t)(unsigned)s0 << 6))[lane];     // SGPR base + lane*4
      }
      #pragma unroll
      for (int k = 0; k < 8; k++){
        float q = myp[4*(c+k) + hh];
        acc0 = fmaf(q, blo(u[k]), acc0);
        acc1 = fmaf(q, bhi(u[k]), acc1);
      }
    }
    __threadfence_block();
  } else {
    // ---- general path (rare): two-pass ----
    float mx = ex, my = ey, mz = ez, mw = ew;
    float cw = 0.f;
    for (int j = lane; j < deg; j += 64){
      int2 er = es[base + j];
      float4 a = *(const float4*)(asn + er.x*4);
      mx = fmaxf(mx, lrelu(a.x+ad4.x)); my = fmaxf(my, lrelu(a.y+ad4.y));
      mz = fmaxf(mz, lrelu(a.z+ad4.z)); mw = fmaxf(mw, lrelu(a.w+ad4.w));
      if (CRIT) cw += __int_as_float(er.y);
    }
    #pragma unroll
    for (int m = 1; m < 64; m <<= 1){
      mx = fmaxf(mx, __shfl_xor(mx, m)); my = fmaxf(my, __shfl_xor(my, m));
      mz = fmaxf(mz, __shfl_xor(mz, m)); mw = fmaxf(mw, __shfl_xor(mw, m));
      if (CRIT) cw += __shfl_xor(cw, m);
    }
    if (CRIT){ if (lane == 0) crit[n] = cw; cr = cw; }
    else cr = crit[n];
    psx = __expf(ex-mx); psy = __expf(ey-my); psz = __expf(ez-mz); psw = __expf(ew-mw);
    float pself = hh < 2 ? (hh == 0 ? psx : psy) : (hh == 2 ? psz : psw);
    unsigned us = (xw + ((size_t)(unsigned)n << 6))[lane];
    acc0 = pself * blo(us); acc1 = pself * bhi(us);
    sx = 0.f; sy = 0.f; sz = 0.f; sw = 0.f;
    for (int j0 = 0; j0 < deg; j0 += 64){
      int clen = deg - j0; if (clen > 64) clen = 64;
      int sreg = 0;
      float p0 = 0.f, p1 = 0.f, p2 = 0.f, p3 = 0.f;
      if (lane < clen){
        sreg = es[base + j0 + lane].x;
        float4 a = *(const float4*)(asn + sreg*4);
        p0 = __expf(lrelu(a.x+ad4.x)-mx);
        p1 = __expf(lrelu(a.y+ad4.y)-my);
        p2 = __expf(lrelu(a.z+ad4.z)-mz);
        p3 = __expf(lrelu(a.w+ad4.w)-mw);
        sx += p0; sy += p1; sz += p2; sw += p3;
      }
      *(float4*)(&myp[4*lane]) = make_float4(p0,p1,p2,p3);
      __threadfence_block();
      int clenR = (clen + 7) & ~7;
      for (int c = 0; c < clenR; c += 8){
        unsigned u[8];
        #pragma unroll
        for (int k = 0; k < 8; k++){
          int s0 = __builtin_amdgcn_readlane(sreg, c + k);
          u[k] = (xw + ((size_t)(unsigned)s0 << 6))[lane];
        }
        #pragma unroll
        for (int k = 0; k < 8; k++){
          float q = myp[4*(c+k) + hh];
          acc0 = fmaf(q, blo(u[k]), acc0);
          acc1 = fmaf(q, bhi(u[k]), acc1);
        }
      }
      __threadfence_block();
    }
  }
  #pragma unroll
  for (int m = 1; m < 64; m <<= 1){
    sx += __shfl_xor(sx, m); sy += __shfl_xor(sy, m);
    sz += __shfl_xor(sz, m); sw += __shfl_xor(sw, m);
  }
  sx += psx; sy += psy; sz += psz; sw += psw;
  float den = (hh < 2 ? (hh == 0 ? sx : sy) : (hh == 2 ? sz : sw)) + 1e-16f;
  float rden = 1.f / den;
  int c0 = 2*lane;
  float2 blv = *(const float2*)(bl + c0);
  float o0 = acc0*rden + blv.x;
  float o1 = acc1*rden + blv.y;
  float su = o0 + o1, sq = o0*o0 + o1*o1;
  #pragma unroll
  for (int m = 1; m < 64; m <<= 1){ su += __shfl_xor(su, m); sq += __shfl_xor(sq, m); }
  float mu  = su * (1.f/128.f);
  float var = sq * (1.f/128.f) - mu*mu; var = var > 0.f ? var : 0.f;
  float inv = rsqrtf(var + 1e-5f);
  float2 rv  = *(const float2*)(h + (size_t)n*128 + c0);
  float2 gv  = *(const float2*)(lng + c0);
  float2 bv2 = *(const float2*)(lnb + c0);
  o0 = (o0-mu)*inv*gv.x + bv2.x + cr + rv.x;
  o1 = (o1-mu)*inv*gv.y + bv2.y + cr + rv.y;
  *(float2*)(&h[(size_t)n*128 + c0]) = make_float2(o0, o1);
  *(unsigned*)(&hb[(size_t)n*128 + c0]) = ((unsigned)f2b(o1) << 16) | f2b(o0);
}

// ---------------- pooling: one block per graph, atomic-free ----------------
__global__ __launch_bounds__(256) void k_pool(
    const float* __restrict__ h, float* __restrict__ gate,
    const int* __restrict__ start, float* __restrict__ out)
{
  __shared__ float red[4];
  __shared__ float sbc;
  __shared__ float4 accs[8][32];
  int b = blockIdx.x;
  int s0 = start[b], s1 = start[b+1];
  int tid = threadIdx.x, lane = tid & 63, wave = tid >> 6;
  float m = -3.0e38f;
  for (int i = s0 + tid; i < s1; i += 256) m = fmaxf(m, gate[i]);
  #pragma unroll
  for (int k = 1; k < 64; k <<= 1) m = fmaxf(m, __shfl_xor(m, k));
  if (lane == 0) red[wave] = m;
  __syncthreads();
  if (tid == 0) sbc = fmaxf(fmaxf(red[0],red[1]), fmaxf(red[2],red[3]));
  __syncthreads();
  float gm = sbc;
  __syncthreads();
  float s = 0.f;
  for (int i = s0 + tid; i < s1; i += 256){
    float p = __expf(gate[i] - gm);
    gate[i] = p;
    s += p;
  }
  #pragma unroll
  for (int k = 1; k < 64; k <<= 1) s += __shfl_xor(s, k);
  if (lane == 0) red[wave] = s;
  __syncthreads();
  if (tid == 0) sbc = red[0]+red[1]+red[2]+red[3];
  __syncthreads();
  float inv = 1.f / (sbc + 1e-16f);
  int c4 = (tid & 31) * 4;
  int g  = tid >> 5;
  float4 acc = make_float4(0.f,0.f,0.f,0.f);
  for (int i = s0 + g; i < s1; i += 8){
    float p = gate[i];
    float4 hv = *(const float4*)(h + (size_t)i*128 + c4);
    acc.x = fmaf(p,hv.x,acc.x); acc.y = fmaf(p,hv.y,acc.y);
    acc.z = fmaf(p,hv.z,acc.z); acc.w = fmaf(p,hv.w,acc.w);
  }
  accs[g][tid & 31] = acc;
  __syncthreads();
  if (g == 0){
    float4 t = acc;
    #pragma unroll
    for (int k = 1; k < 8; k++){
      float4 o = accs[k][tid & 31];
      t.x += o.x; t.y += o.y; t.z += o.z; t.w += o.w;
    }
    t.x *= inv; t.y *= inv; t.z *= inv; t.w *= inv;
    *(float4*)(out + b*128 + c4) = t;
  }
}

extern "C" void kernel_launch(void* const* d_in, const int* in_sizes, int n_in,
                              void* d_out, int out_size, void* d_ws, size_t ws_size,
                              hipStream_t stream){
  (void)in_sizes; (void)n_in; (void)out_size; (void)ws_size;
  const float* x    = (const float*)d_in[0];
  const float* ea   = (const float*)d_in[1];
  const float* Win  = (const float*)d_in[2];
  const float* b_in = (const float*)d_in[3];
  const float* We1  = (const float*)d_in[4];
  const float* be1  = (const float*)d_in[5];
  const float* We2  = (const float*)d_in[6];
  const float* be2  = (const float*)d_in[7];
  const float* Wl   = (const float*)d_in[8];
  const float* a_src= (const float*)d_in[9];
  const float* a_dst= (const float*)d_in[10];
  const float* bl   = (const float*)d_in[11];
  const float* lng  = (const float*)d_in[12];
  const float* lnb  = (const float*)d_in[13];
  const float* Wg1  = (const float*)d_in[14];
  const float* bg1  = (const float*)d_in[15];
  const float* Wg2  = (const float*)d_in[16];
  const float* bg2  = (const float*)d_in[17];
  const int*   ei   = (const int*)d_in[18];
  const int*   batch= (const int*)d_in[19];
  float* out = (float*)d_out;

  char* w = (char*)d_ws;
  auto alloc = [&](size_t bytes){ char* p = w; w += (bytes + 255) & ~(size_t)255; return p; };
  float* h    = (float*)alloc((size_t)N_NODES*128*4);
  unsigned short* hb  = (unsigned short*)alloc((size_t)N_NODES*128*2);
  unsigned short* xpb = (unsigned short*)alloc((size_t)N_NODES*128*2);  // also hosts xb pre-layers
  float* asn  = (float*)alloc((size_t)N_NODES*4*4);
  float* adn  = (float*)alloc((size_t)N_NODES*4*4);
  float* crit = (float*)alloc((size_t)N_NODES*4);
  int*   cnt  = (int*)alloc((size_t)N_NODES*4);
  int*   incl = (int*)alloc((size_t)N_NODES*4);
  int*   part = (int*)alloc(256*4);
  int*   pexc = (int*)alloc(256*4);
  int*   off  = (int*)alloc((size_t)(N_NODES+1)*4);
  int*   rank = (int*)alloc((size_t)N_EDGES*4);
  int2*  es   = (int2*)alloc((size_t)N_EDGES*8);
  float* gate = (float*)alloc((size_t)N_NODES*4);
  int*   start= (int*)alloc((size_t)(N_B+1)*4);
  unsigned short* WinT = (unsigned short*)alloc((size_t)128*128*2);
  unsigned short* WlT  = (unsigned short*)alloc((size_t)4*144*128*2);
  unsigned short* Wg1T = (unsigned short*)alloc((size_t)64*128*2);
  unsigned short* xb = xpb;

  int nb_n = (N_NODES + 255)/256;   // 196
  int nb_w = (N_NODES + 3)/4;       // 12500
  int nb_g = (N_NODES + 63)/64;     // 782
  int nb_c = (1698304 + 255)/256;   // 6634
  int nb_4e = (200000 + 255)/256;   // 782

  k_conv<<<nb_c,256,0,stream>>>(x, Win, Wl, a_src, a_dst, Wg1, xb, WinT, WlT, Wg1T);
  k_setup<<<nb_n,256,0,stream>>>(batch, start, cnt);
  k_hist<<<nb_4e,256,0,stream>>>(ei, cnt, rank);
  k_mgemm<8,0><<<nb_g,256,0,stream>>>(xb, WinT, b_in, h, hb,
                                      nullptr, nullptr, nullptr, nullptr, nullptr, nullptr);
  k_scan1<<<nb_n,256,0,stream>>>(cnt, incl, part);
  k_scan2<<<1,256,0,stream>>>(part, pexc, nb_n);
  k_scan3<<<nb_n,256,0,stream>>>(cnt, incl, pexc, off);
  k_fill<<<nb_4e,256,0,stream>>>(ea, We1, be1, We2, be2, ei, off, rank, es);
  for (int l = 0; l < 4; l++){
    k_mgemm<9,1><<<nb_g,256,0,stream>>>(hb, WlT + (size_t)l*144*128, nullptr, nullptr, nullptr,
                                        xpb, asn, adn, nullptr, nullptr, nullptr);
    if (l == 0)
      k_aggr<true><<<nb_w,256,0,stream>>>(xpb, asn, adn, off, es,
                                          bl + l*128, lng + l*128, lnb + l*128, crit, h, hb);
    else
      k_aggr<false><<<nb_w,256,0,stream>>>(xpb, asn, adn, off, es,
                                           bl + l*128, lng + l*128, lnb + l*128, crit, h, hb);
  }
  k_mgemm<4,2><<<nb_g,256,0,stream>>>(hb, Wg1T, bg1, nullptr, nullptr,
                                      nullptr, nullptr, nullptr, Wg2, bg2, gate);
  k_pool<<<N_B,256,0,stream>>>(h, gate, start, out);
}